// Round 6
// baseline (3806.794 us; speedup 1.0000x reference)
//
#include <hip/hip_runtime.h>
#include <stdint.h>

// ---------------------------------------------------------------------------
// ODE-RNN encoder, f32 I/O, bf16 MFMA internals.
// R23: 1024-thread ode block; 16 waves, wave tile M64 x N32.
// R22 post-mortem: M=64 @ 8 waves validated the GEMM model exactly (MFMA
// 29.4K measured vs 29.8K predicted per eval) but natural reg demand (~148
// arch + 64 acc) blew the cap -> VGPR_Count=128 (capped), FETCH 39->510MB
// (scratch), epilogue latency chains +spill reloads = 66K cyc/eval.
// R23 keeps the same per-block tile (M=64: vmem 25.6K ~ MFMA 29.8K balanced;
// per-CU traffic per kk unchanged: 128 MFMA, 32KB B-loads) but splits it
// over 16 waves: per-thread state HALVES (acc 32A, h 32V f32, bb 16, prm 8,
// a 8) -> ~120 total <= 128 -> 4 waves/SIMD NATURALLY resident:
//  (a) no spills, (b) 2x TLP hides epilogue latency chains, (c) per-thread
//  epilogue work halves. LDS: As 64K + Ks 66K + red 8K + stat = ~138.6KB.
// Session laws: occupancy pinned by reg grant (R17-R21); forced-split
// spill catastrophe (R18); M=16 kills B amortization (R20); params->regs
// helps (R21); cycle model T = max(vmem, MFMA) + E with E latency-bound.
// Carried: plain-load prefetch sink (R11); no global_load_lds (R12/13);
// 2-slab B dbuf; no global RK4 state (R15); GRU simple (R15/R16).
// ---------------------------------------------------------------------------

typedef __bf16 bf16x8 __attribute__((ext_vector_type(8)));
typedef float floatx4 __attribute__((ext_vector_type(4)));

#define BP 40   // gru padded B row (ushorts)
#define KSP 516 // Ks row stride (uints): 2-way bank max (free)

static __device__ __forceinline__ float bf2f(unsigned short u) {
  union { unsigned int u32; float f; } c;
  c.u32 = ((unsigned int)u) << 16;
  return c.f;
}
static __device__ __forceinline__ unsigned short f2bf(float f) {
  union { __bf16 h; unsigned short u; } c;
  c.h = (__bf16)f;  // RNE
  return c.u;
}
// packed-bf16-pair helpers (params live as u32 = lo|hi<<16)
static __device__ __forceinline__ float lo_bf(unsigned int u) {
  union { unsigned int i; float f; } c; c.i = u << 16; return c.f;
}
static __device__ __forceinline__ float hi_bf(unsigned int u) {
  union { unsigned int i; float f; } c; c.i = u & 0xffff0000u; return c.f;
}
static __device__ __forceinline__ unsigned int pk2(float a, float b) {
  return (unsigned int)f2bf(a) | ((unsigned int)f2bf(b) << 16);
}

// LDS-only barrier: does NOT drain vmcnt, so global prefetches stay in flight.
static __device__ __forceinline__ void barrier_lds() {
  __asm__ volatile("s_waitcnt lgkmcnt(0)\n\ts_barrier" ::: "memory");
}

// VALU-only 16-lane row sum via DPP row_shr chain; sum lands in lane ml==15.
static __device__ __forceinline__ float row16_sum(float v) {
  union { float f; int i; } c, d;
  c.f = v;
  d.i = __builtin_amdgcn_update_dpp(0, c.i, 0x111, 0xf, 0xf, true); c.f += d.f;
  d.i = __builtin_amdgcn_update_dpp(0, c.i, 0x112, 0xf, 0xf, true); c.f += d.f;
  d.i = __builtin_amdgcn_update_dpp(0, c.i, 0x114, 0xf, 0xf, true); c.f += d.f;
  d.i = __builtin_amdgcn_update_dpp(0, c.i, 0x118, 0xf, 0xf, true); c.f += d.f;
  return c.f;
}

// ---------------------------------------------------------------------------
// tile_weight: W (K=512 x N=512, f32 row-major) -> bf16 tiled
// [kk(16)][nt(32)][qd(4)][ml(16)][8]; element (kk,nt,qd,ml,j) = W[kk*32+qd*8+j][nt*16+ml]
// ---------------------------------------------------------------------------
__global__ void tile_weight(const float* __restrict__ src, unsigned short* __restrict__ dst) {
  int t = blockIdx.x * 256 + threadIdx.x;  // 0..32767
  int ml = t & 15, qd = (t >> 4) & 3;
  int nt = (t >> 6) & 31, kk = t >> 11;
  int n = nt * 16 + ml;
  int k0 = kk * 32 + qd * 8;
  unsigned short o[8] __attribute__((aligned(16)));
#pragma unroll
  for (int j = 0; j < 8; ++j) o[j] = f2bf(src[(size_t)(k0 + j) * 512 + n]);
  *(uint4*)(dst + (size_t)t * 8) = *(const uint4*)o;
}

// ---------------------------------------------------------------------------
// transpose + f32->bf16 (GRU weights, [n][k] flat layout)
// ---------------------------------------------------------------------------
__global__ void transpose_f2b(const float* __restrict__ src, unsigned short* __restrict__ dst,
                              int R, int C) {
  __shared__ float t[32][33];
  int c0 = blockIdx.x * 32, r0 = blockIdx.y * 32;
  int tx = threadIdx.x, ty = threadIdx.y;  // 32 x 8
#pragma unroll
  for (int i = 0; i < 32; i += 8) t[ty + i][tx] = src[(size_t)(r0 + ty + i) * C + c0 + tx];
  __syncthreads();
#pragma unroll
  for (int i = 0; i < 32; i += 8) dst[(size_t)(c0 + ty + i) * R + r0 + tx] = f2bf(t[tx][ty + i]);
}

// ---------------------------------------------------------------------------
// obs embed: y = leaky(LN(xs @ W + b)) (f32 in, bf16 out), one wave per row
// ---------------------------------------------------------------------------
__global__ __launch_bounds__(256) void obs_embed(
    const float* __restrict__ xs, const float* __restrict__ W,
    const float* __restrict__ bias, const float* __restrict__ gam,
    const float* __restrict__ bet, unsigned short* __restrict__ Y) {
  __shared__ float Wl[4096];
  const int tid = threadIdx.x, lane = tid & 63, wv = tid >> 6;
#pragma unroll
  for (int i = 0; i < 16; ++i) Wl[i * 256 + tid] = W[i * 256 + tid];
  __syncthreads();
  size_t row = (size_t)blockIdx.x * 4 + wv;
  float xf[8];
  {
    const float* xp = xs + row * 8;
#pragma unroll
    for (int k = 0; k < 8; ++k) xf[k] = xp[k];
  }
  int n0 = lane * 8;
  float a[8];
#pragma unroll
  for (int j = 0; j < 8; ++j) a[j] = bias[n0 + j];
#pragma unroll
  for (int k = 0; k < 8; ++k)
#pragma unroll
    for (int j = 0; j < 8; ++j) a[j] += xf[k] * Wl[k * 512 + n0 + j];
  float s1 = 0.f, s2 = 0.f;
#pragma unroll
  for (int j = 0; j < 8; ++j) { s1 += a[j]; s2 += a[j] * a[j]; }
#pragma unroll
  for (int off = 1; off < 64; off <<= 1) { s1 += __shfl_xor(s1, off); s2 += __shfl_xor(s2, off); }
  float mean = s1 * (1.f / 512.f);
  float rstd = rsqrtf(s2 * (1.f / 512.f) - mean * mean + 1e-5f);
  unsigned short o[8] __attribute__((aligned(16)));
#pragma unroll
  for (int j = 0; j < 8; ++j) {
    float v = (a[j] - mean) * rstd * gam[n0 + j] + bet[n0 + j];
    v = v > 0.f ? v : 0.01f * v;
    o[j] = f2bf(v);
  }
  *(uint4*)(Y + row * 512 + n0) = *(const uint4*)o;
}

// ---------------------------------------------------------------------------
// ODE megakernel, M=64 per block, 16 waves (1024 thr), wave = M64 x N32
// (nt = 2*wv, 2*wv+1). A (64x512) in tiled LDS; B streams global->VGPR dbuf.
// ---------------------------------------------------------------------------

// element (row, n) address in tiled A (ushort index), row < 64
static __device__ __forceinline__ int a_addr(int row, int n) {
  return (((row >> 4) * 16 + (n >> 5)) * 4 + ((n >> 3) & 3)) * 128 + (row & 15) * 8 + (n & 7);
}

static __device__ __forceinline__ void bload(const unsigned short* __restrict__ Wt, int kk,
                                             int wvoff, bf16x8 (&b)[2]) {
  const unsigned short* p = Wt + (size_t)kk * 16384 + wvoff;
  b[0] = *(const bf16x8*)(p);
  b[1] = *(const bf16x8*)(p + 512);
}

// acc initialized to bias (splat) -> bias-add pass and zero-init both free.
// bb must hold Wt slabs {0,1} on entry; holds Wnext slabs {0,1} on exit.
static __device__ __forceinline__ void gemmS(const unsigned short* __restrict__ Wt,
                                             const unsigned short* __restrict__ Wnext,
                                             const unsigned short* As, int wvoff, int lane,
                                             const float (&bias)[2],
                                             bf16x8 (&bb)[2][2], floatx4 (&acc)[4][2]) {
#pragma unroll
  for (int mi = 0; mi < 4; ++mi)
#pragma unroll
    for (int j = 0; j < 2; ++j)
      acc[mi][j] = (floatx4){bias[j], bias[j], bias[j], bias[j]};
#pragma unroll 2
  for (int kk = 0; kk < 16; ++kk) {  // unroll 2 (dbuf parity), NOT full (R5-R8)
#pragma unroll
    for (int mh = 0; mh < 2; ++mh) {  // a-frags chunked 2 at a time (reg cap)
      bf16x8 a0 = *(const bf16x8*)&As[((2 * mh) * 16 + kk) * 512 + lane * 8];
      bf16x8 a1 = *(const bf16x8*)&As[((2 * mh + 1) * 16 + kk) * 512 + lane * 8];
#pragma unroll
      for (int j = 0; j < 2; ++j) {
        acc[2 * mh][j] =
            __builtin_amdgcn_mfma_f32_16x16x32_bf16(a0, bb[kk & 1][j], acc[2 * mh][j], 0, 0, 0);
        acc[2 * mh + 1][j] =
            __builtin_amdgcn_mfma_f32_16x16x32_bf16(a1, bb[kk & 1][j], acc[2 * mh + 1][j], 0, 0, 0);
      }
    }
    // refill the just-consumed slot: kk+2 of this weight, or next weight's 0/1
    if (kk < 14) bload(Wt, kk + 2, wvoff, bb[kk & 1]);
    else bload(Wnext, kk - 14, wvoff, bb[kk & 1]);
  }
}

// LN + leaky epilogue; 16-wave reduction; gamma/beta from registers.
static __device__ __forceinline__ void ln_epi(floatx4 (&acc)[4][2], unsigned short* As,
                                              const float (&gm)[2], const float (&bt)[2],
                                              int wv, int lane, int tid,
                                              float2* red, float* stat) {
  const int ml = lane & 15, qd = lane >> 4;
#pragma unroll
  for (int mi = 0; mi < 4; ++mi)
#pragma unroll
    for (int r = 0; r < 4; ++r) {
      float x0 = acc[mi][0][r], x1 = acc[mi][1][r];
      float s1 = row16_sum(x0 + x1);
      float s2 = row16_sum(x0 * x0 + x1 * x1);
      if (ml == 15) red[(mi * 16 + 4 * qd + r) * 16 + wv] = make_float2(s1, s2);
    }
  barrier_lds();  // red visible; all waves past their As a-frag reads
  if (tid < 64) {
    float S1 = 0.f, S2 = 0.f;
#pragma unroll
    for (int w = 0; w < 16; ++w) { float2 v = red[tid * 16 + w]; S1 += v.x; S2 += v.y; }
    float mean = S1 * (1.f / 512.f);
    float var = S2 * (1.f / 512.f) - mean * mean;
    stat[tid * 2] = mean;
    stat[tid * 2 + 1] = rsqrtf(var + 1e-5f);
  }
  barrier_lds();
#pragma unroll
  for (int mi = 0; mi < 4; ++mi) {
    float mean[4], rstd[4];
#pragma unroll
    for (int r = 0; r < 4; ++r) {
      int row = mi * 16 + 4 * qd + r;
      mean[r] = stat[row * 2];
      rstd[r] = stat[row * 2 + 1];
    }
#pragma unroll
    for (int j = 0; j < 2; ++j) {
      int n = (2 * wv + j) * 16 + ml;
#pragma unroll
      for (int r = 0; r < 4; ++r) {
        float x = (acc[mi][j][r] - mean[r]) * (rstd[r] * gm[j]) + bt[j];
        x = x > 0.f ? x : 0.01f * x;
        As[a_addr(mi * 16 + 4 * qd + r, n)] = f2bf(x);
      }
    }
  }
  barrier_lds();  // As writes visible
}

// RK4 stage: kv = acc (bout folded into acc init); h fp32 regs; ksum packed
// bf16 pairs in LDS Ks (per-thread slots, no extra barriers); writes y into
// As; final stage also writes h_ode to Yb.
static __device__ __forceinline__ void stage_epi(floatx4 (&acc)[4][2], float (&h)[4][2][4],
                                                 unsigned int* Ks, unsigned short* As,
                                                 unsigned short* Yb, size_t m0,
                                                 int stg, bool last, int wv, int lane) {
  const int ml = lane & 15, qd = lane >> 4;
  barrier_lds();  // K-loop has no barriers: ensure all waves done reading As
#pragma unroll
  for (int mi = 0; mi < 4; ++mi)
#pragma unroll
    for (int j = 0; j < 2; ++j) {
      int n = (2 * wv + j) * 16 + ml;
#pragma unroll
      for (int rp = 0; rp < 2; ++rp) {
        int kidx = (mi * 8 + qd * 2 + rp) * KSP + n;
        float kv0 = acc[mi][j][2 * rp];
        float kv1 = acc[mi][j][2 * rp + 1];
        unsigned int pk = (stg != 0) ? Ks[kidx] : 0u;
        float s0 = bf2f((unsigned short)(pk & 0xffffu));
        float s1 = bf2f((unsigned short)(pk >> 16));
        float h0 = h[mi][j][2 * rp], h1 = h[mi][j][2 * rp + 1];
        float y0, y1;
        if (stg == 0)      { s0 = kv0;        s1 = kv1;        y0 = h0 + 0.125f * kv0; y1 = h1 + 0.125f * kv1; }
        else if (stg == 1) { s0 += 2.f * kv0; s1 += 2.f * kv1; y0 = h0 + 0.125f * kv0; y1 = h1 + 0.125f * kv1; }
        else if (stg == 2) { s0 += 2.f * kv0; s1 += 2.f * kv1; y0 = h0 + 0.25f * kv0;  y1 = h1 + 0.25f * kv1; }
        else {
          h0 += (1.f / 24.f) * (s0 + kv0);  // dt/6, dt=0.25
          h1 += (1.f / 24.f) * (s1 + kv1);
          h[mi][j][2 * rp] = h0; h[mi][j][2 * rp + 1] = h1;
          y0 = h0; y1 = h1;
        }
        if (stg != 3) Ks[kidx] = (unsigned int)f2bf(s0) | ((unsigned int)f2bf(s1) << 16);
        int row = mi * 16 + 4 * qd + 2 * rp;
        As[a_addr(row, n)] = f2bf(y0);
        As[a_addr(row + 1, n)] = f2bf(y1);
        if (last && stg == 3) {
          Yb[(m0 + row) * 512 + n] = f2bf(y0);
          Yb[(m0 + row + 1) * 512 + n] = f2bf(y1);
        }
      }
    }
  barrier_lds();  // As writes visible
}

__global__ __launch_bounds__(1024) void ode_mega(
    unsigned short* Yb, const unsigned short* __restrict__ W1t,
    const unsigned short* __restrict__ W2t, const unsigned short* __restrict__ Wot,
    const float* __restrict__ b1, const float* __restrict__ tr, const float* __restrict__ g1,
    const float* __restrict__ be1, const float* __restrict__ b2, const float* __restrict__ g2,
    const float* __restrict__ be2, const float* __restrict__ bo) {
  __shared__ __align__(16) unsigned short As[32768];  // 64KB tiled A (64 rows)
  __shared__ float2 red[1024];                        // 8KB: 64 rows x 16 waves
  __shared__ float stat[128];                         // 512B
  __shared__ __align__(16) unsigned int Ks[32 * KSP]; // 66KB RK4 ksum
  // total ~138.6KB <= 160KB; 16 waves resident = 4 waves/SIMD

  const int tid = threadIdx.x;
  const int lane = tid & 63;
  const int wv = tid >> 6;  // 0..15
  const int ml = lane & 15;
  const int qd = lane >> 4;
  const size_t m0 = (size_t)blockIdx.x * 64;
  const int wvoff = wv * 1024 + lane * 8;  // (2wv)*512 + lane*8

  // start weight prefetch immediately
  bf16x8 bb[2][2];
  bload(W1t, 0, wvoff, bb[0]);
  bload(W1t, 1, wvoff, bb[1]);

  // per-thread params: 2 n-positions x 8 params -> 8 packed u32 regs.
  // prm[j] = { (b1|tr), (g1|be1), (b2|g2), (be2|bo) } at n=(2wv+j)*16+ml
  unsigned int prm[2][4];
#pragma unroll
  for (int j = 0; j < 2; ++j) {
    int n = (2 * wv + j) * 16 + ml;
    prm[j][0] = pk2(b1[n], tr[n]);
    prm[j][1] = pk2(g1[n], be1[n]);
    prm[j][2] = pk2(b2[n], g2[n]);
    prm[j][3] = pk2(be2[n], bo[n]);
  }

  // stage As: thread owns row r = tid>>4, chunks c = (tid&15) + i*16, i=0..3
  {
    int r = tid >> 4;       // 0..63
    int c0 = tid & 15;
#pragma unroll
    for (int i = 0; i < 4; ++i) {
      int c = c0 + i * 16;  // 0..63
      uint4 v = *(const uint4*)(Yb + (m0 + r) * 512 + c * 8);
      int dst = (((r >> 4) * 16 + (c >> 2)) * 4 + (c & 3)) * 128 + (r & 15) * 8;
      *(uint4*)(As + dst) = v;
    }
  }
  barrier_lds();

  float h[4][2][4];  // fp32 ODE state, MFMA C-layout (32 elems/thread)
#pragma unroll
  for (int mi = 0; mi < 4; ++mi)
#pragma unroll
    for (int j = 0; j < 2; ++j) {
      int n = (2 * wv + j) * 16 + ml;
#pragma unroll
      for (int r = 0; r < 4; ++r) h[mi][j][r] = bf2f(As[a_addr(mi * 16 + 4 * qd + r, n)]);
    }

  for (int e = 0; e < 16; ++e) {  // 4 RK4 steps x 4 stages
    int stg = e & 3;
    float tval = 0.25f * (float)(e >> 2) + ((stg == 3) ? 0.25f : (stg ? 0.125f : 0.f));
    floatx4 acc[4][2];
    float bias[2], gm[2], bt[2];

#pragma unroll
    for (int j = 0; j < 2; ++j) {  // layer-1 params (time row folded into bias)
      unsigned int p0 = prm[j][0], p1 = prm[j][1];
      bias[j] = lo_bf(p0) + tval * hi_bf(p0);
      gm[j] = lo_bf(p1);
      bt[j] = hi_bf(p1);
    }
    gemmS(W1t, W2t, As, wvoff, lane, bias, bb, acc);
    ln_epi(acc, As, gm, bt, wv, lane, tid, red, stat);

#pragma unroll
    for (int j = 0; j < 2; ++j) {  // layer-2 params
      unsigned int p2 = prm[j][2], p3 = prm[j][3];
      bias[j] = lo_bf(p2);
      gm[j] = hi_bf(p2);
      bt[j] = lo_bf(p3);
    }
    gemmS(W2t, Wot, As, wvoff, lane, bias, bb, acc);
    ln_epi(acc, As, gm, bt, wv, lane, tid, red, stat);

    float bo2[2];
#pragma unroll
    for (int j = 0; j < 2; ++j) bo2[j] = hi_bf(prm[j][3]);
    gemmS(Wot, W1t, As, wvoff, lane, bo2, bb, acc);  // preloads next eval's W1
    stage_epi(acc, h, Ks, As, Yb, m0, stg, e == 15, wv, lane);
  }
}

// ---------------------------------------------------------------------------
// GRU step: gi = y_t @ W_ih, gh = h_prev @ W_hh, gates.
// grid (32, 8): 32 rows x 64 gate-cols per block, 4 waves.
// ---------------------------------------------------------------------------
__global__ __launch_bounds__(256) void gru_step(
    const unsigned short* __restrict__ Yt, const float* __restrict__ hprev,
    float* __restrict__ hnew, const unsigned short* __restrict__ Wiht,
    const unsigned short* __restrict__ Whht, const float* __restrict__ bih,
    const float* __restrict__ bhh) {
  __shared__ __align__(16) unsigned short Ay[32 * BP];
  __shared__ __align__(16) unsigned short Ah[32 * BP];
  __shared__ __align__(16) unsigned short Bg[6 * 64 * BP];
  const int tid = threadIdx.x, lane = tid & 63, wv = tid >> 6;
  const int ml = lane & 15, qd = lane >> 4;
  const int m0 = blockIdx.x * 32;
  const int j0 = blockIdx.y * 64;

  floatx4 acc[2][6];
#pragma unroll
  for (int mi = 0; mi < 2; ++mi)
#pragma unroll
    for (int g = 0; g < 6; ++g) acc[mi][g] = 0.f;

  for (int kk = 0; kk < 16; ++kk) {
    __syncthreads();
#pragma unroll
    for (int c = 0; c < 7; ++c) {
      int id = c * 256 + tid;
      if (id < 128) {
        int r = id >> 2, kc = id & 3;
        *(uint4*)(Ay + r * BP + kc * 8) =
            *(const uint4*)(Yt + (size_t)(m0 + r) * 512 + kk * 32 + kc * 8);
      } else if (id < 256) {
        int id2 = id - 128;
        int r = id2 >> 2, kc = id2 & 3;
        const float* s = hprev + (size_t)(m0 + r) * 512 + kk * 32 + kc * 8;
        unsigned short o[8] __attribute__((aligned(16)));
#pragma unroll
        for (int j = 0; j < 8; ++j) o[j] = f2bf(s[j]);
        *(uint4*)(Ah + r * BP + kc * 8) = *(const uint4*)o;
      } else {
        int id2 = id - 256;
        int g = id2 >> 8;
        int rem = id2 & 255;
        int r = rem >> 2, kc = rem & 3;
        const unsigned short* mat = (g < 3) ? Wiht : Whht;
        int gate = (g < 3) ? g : (g - 3);
        *(uint4*)(Bg + g * (64 * BP) + r * BP + kc * 8) =
            *(const uint4*)(mat + (size_t)(gate * 512 + j0 + r) * 512 + kk * 32 + kc * 8);
      }
    }
    __syncthreads();
    bf16x8 ay[2], ah[2];
#pragma unroll
    for (int mi = 0; mi < 2; ++mi) {
      ay[mi] = *(const bf16x8*)&Ay[(16 * mi + ml) * BP + qd * 8];
      ah[mi] = *(const bf16x8*)&Ah[(16 * mi + ml) * BP + qd * 8];
    }
#pragma unroll
    for (int g = 0; g < 6; ++g) {
      bf16x8 b = *(const bf16x8*)&Bg[g * (64 * BP) + (16 * wv + ml) * BP + qd * 8];
#pragma unroll
      for (int mi = 0; mi < 2; ++mi)
        acc[mi][g] = __builtin_amdgcn_mfma_f32_16x16x32_bf16((g < 3) ? ay[mi] : ah[mi], b,
                                                             acc[mi][g], 0, 0, 0);
    }
  }
  int j = j0 + 16 * wv + ml;
  float bi_r = bih[j], bi_z = bih[512 + j], bi_n = bih[1024 + j];
  float bh_r = bhh[j], bh_z = bhh[512 + j], bh_n = bhh[1024 + j];
#pragma unroll
  for (int mi = 0; mi < 2; ++mi)
#pragma unroll
    for (int r = 0; r < 4; ++r) {
      size_t row = (size_t)(m0 + 16 * mi + 4 * qd + r);
      float rg = acc[mi][0][r] + bi_r + acc[mi][3][r] + bh_r;
      rg = 1.f / (1.f + __expf(-rg));
      float zg = acc[mi][1][r] + bi_z + acc[mi][4][r] + bh_z;
      zg = 1.f / (1.f + __expf(-zg));
      float ng = tanhf(acc[mi][2][r] + bi_n + rg * (acc[mi][5][r] + bh_n));
      float hp = hprev[row * 512 + j];
      hnew[row * 512 + j] = (1.f - zg) * ng + zg * hp;
    }
}

__global__ void zero_h(float* hf) {
  int i = blockIdx.x * 256 + threadIdx.x;
  hf[i] = 0.f;
}

// ---------------------------------------------------------------------------
extern "C" void kernel_launch(void* const* d_in, const int* in_sizes, int n_in,
                              void* d_out, int out_size, void* d_ws, size_t ws_size,
                              hipStream_t stream) {
  (void)in_sizes; (void)n_in; (void)out_size; (void)ws_size;
  const float* xs    = (const float*)d_in[0];
  const float* obsW  = (const float*)d_in[1];
  const float* obsb  = (const float*)d_in[2];
  const float* obsg  = (const float*)d_in[3];
  const float* obsbe = (const float*)d_in[4];
  const float* W1    = (const float*)d_in[5];
  const float* b1    = (const float*)d_in[6];
  const float* g1    = (const float*)d_in[7];
  const float* be1   = (const float*)d_in[8];
  const float* W2    = (const float*)d_in[9];
  const float* b2    = (const float*)d_in[10];
  const float* g2    = (const float*)d_in[11];
  const float* be2   = (const float*)d_in[12];
  const float* Wo    = (const float*)d_in[13];
  const float* bo    = (const float*)d_in[14];
  const float* Wih   = (const float*)d_in[15];
  const float* bih   = (const float*)d_in[16];
  const float* Whh   = (const float*)d_in[17];
  const float* bhh   = (const float*)d_in[18];

  char* p = (char*)d_ws;
  auto take = [&](size_t bytes) { char* q = p; p += (bytes + 255) & ~(size_t)255; return q; };
  unsigned short* W1t  = (unsigned short*)take((size_t)512 * 512 * 2);
  unsigned short* W2t  = (unsigned short*)take((size_t)512 * 512 * 2);
  unsigned short* Wot  = (unsigned short*)take((size_t)512 * 512 * 2);
  unsigned short* Wiht = (unsigned short*)take((size_t)1536 * 512 * 2);
  unsigned short* Whht = (unsigned short*)take((size_t)1536 * 512 * 2);
  float* hf0 = (float*)take((size_t)1024 * 512 * 4);
  float* hf1 = (float*)take((size_t)1024 * 512 * 4);
  unsigned short* Yb = (unsigned short*)take((size_t)65536 * 512 * 2);

  dim3 tb(32, 8);
  tile_weight<<<128, 256, 0, stream>>>(W1, W1t);  // first 512 of 513 rows
  tile_weight<<<128, 256, 0, stream>>>(W2, W2t);
  tile_weight<<<128, 256, 0, stream>>>(Wo, Wot);
  transpose_f2b<<<dim3(48, 16), tb, 0, stream>>>(Wih, Wiht, 512, 1536);
  transpose_f2b<<<dim3(48, 16), tb, 0, stream>>>(Whh, Whht, 512, 1536);

  obs_embed<<<16384, 256, 0, stream>>>(xs, obsW, obsb, obsg, obsbe, Yb);

  // tr = W1 row 512 (time row), folded into layer-1 bias per eval.
  ode_mega<<<1024, 1024, 0, stream>>>(Yb, W1t, W2t, Wot, b1, W1 + 512 * 512, g1, be1, b2, g2,
                                      be2, bo);

  zero_h<<<2048, 256, 0, stream>>>(hf0);
  float* hf[2] = {hf0, hf1};
  for (int t = 0; t < 64; ++t) {
    int s = t & 1, d = s ^ 1;
    float* hn = (t == 63) ? (float*)d_out : hf[d];
    gru_step<<<dim3(32, 8), 256, 0, stream>>>(Yb + (size_t)t * 1024 * 512, hf[s], hn, Wiht, Whht,
                                              bih, bhh);
  }
}

// Round 7
// 3390.939 us; speedup vs baseline: 1.1226x; 1.1226x over previous
//
#include <hip/hip_runtime.h>
#include <stdint.h>

// ---------------------------------------------------------------------------
// ODE-RNN encoder, f32 I/O, bf16 MFMA internals.
// R24 = R22 (M=64, 512thr, 8 waves, wave M64xN64) with arch-VGPR demand
// shaved to fit the cap NATURALLY.
// CONSOLIDATED REGISTER LAW (R17-R23): arch-VGPR cap/wave = 65536/threads
// (512thr->128, 1024thr->64); AGPRs counted SEPARATELY; natural alloc <= cap
// => no spills (R17/19/21); demand > cap => GB-scale scratch (R22: 148>128,
// 510MB; R23: ~90>64, 1.7GB). Occupancy grant: ~24% @ 512thr regardless.
// R24 shaves R22's ~148 arch demand to ~122:
//  * prm 16 regs -> LDS Psu (packed u32 pairs; per-eval transient reads;
//    all qd-groups read same addrs -> LDS broadcast, free)
//  * a-frags chunked 2-at-a-time in gemmS (16 -> 8 regs)
// Everything else R22-verbatim: only mechanism tested = spill removal.
// Cycle model: T_eval = max(vmem 25.6K, MFMA 29.4K) + E; R22 E incl spills
// ~60K; clean target ~45K -> ode ~2100-2300us.
// Carried: plain-load prefetch sink (R11); no global_load_lds (R12/13);
// 2-slab B dbuf; no global RK4 state (R15); GRU simple (R15/R16); M=16
// kills B amortization (R20); acc-init=bias splat (R22).
// ---------------------------------------------------------------------------

typedef __bf16 bf16x8 __attribute__((ext_vector_type(8)));
typedef float floatx4 __attribute__((ext_vector_type(4)));

#define BP 40   // gru padded B row (ushorts)
#define KSP 516 // Ks row stride (uints): 2-way bank max (free)

static __device__ __forceinline__ float bf2f(unsigned short u) {
  union { unsigned int u32; float f; } c;
  c.u32 = ((unsigned int)u) << 16;
  return c.f;
}
static __device__ __forceinline__ unsigned short f2bf(float f) {
  union { __bf16 h; unsigned short u; } c;
  c.h = (__bf16)f;  // RNE
  return c.u;
}
// packed-bf16-pair helpers (params live as u32 = lo|hi<<16)
static __device__ __forceinline__ float lo_bf(unsigned int u) {
  union { unsigned int i; float f; } c; c.i = u << 16; return c.f;
}
static __device__ __forceinline__ float hi_bf(unsigned int u) {
  union { unsigned int i; float f; } c; c.i = u & 0xffff0000u; return c.f;
}
static __device__ __forceinline__ unsigned int pk2(float a, float b) {
  return (unsigned int)f2bf(a) | ((unsigned int)f2bf(b) << 16);
}

// LDS-only barrier: does NOT drain vmcnt, so global prefetches stay in flight.
static __device__ __forceinline__ void barrier_lds() {
  __asm__ volatile("s_waitcnt lgkmcnt(0)\n\ts_barrier" ::: "memory");
}

// VALU-only 16-lane row sum via DPP row_shr chain; sum lands in lane ml==15.
static __device__ __forceinline__ float row16_sum(float v) {
  union { float f; int i; } c, d;
  c.f = v;
  d.i = __builtin_amdgcn_update_dpp(0, c.i, 0x111, 0xf, 0xf, true); c.f += d.f;
  d.i = __builtin_amdgcn_update_dpp(0, c.i, 0x112, 0xf, 0xf, true); c.f += d.f;
  d.i = __builtin_amdgcn_update_dpp(0, c.i, 0x114, 0xf, 0xf, true); c.f += d.f;
  d.i = __builtin_amdgcn_update_dpp(0, c.i, 0x118, 0xf, 0xf, true); c.f += d.f;
  return c.f;
}

// ---------------------------------------------------------------------------
// tile_weight: W (K=512 x N=512, f32 row-major) -> bf16 tiled
// [kk(16)][nt(32)][qd(4)][ml(16)][8]; element (kk,nt,qd,ml,j) = W[kk*32+qd*8+j][nt*16+ml]
// ---------------------------------------------------------------------------
__global__ void tile_weight(const float* __restrict__ src, unsigned short* __restrict__ dst) {
  int t = blockIdx.x * 256 + threadIdx.x;  // 0..32767
  int ml = t & 15, qd = (t >> 4) & 3;
  int nt = (t >> 6) & 31, kk = t >> 11;
  int n = nt * 16 + ml;
  int k0 = kk * 32 + qd * 8;
  unsigned short o[8] __attribute__((aligned(16)));
#pragma unroll
  for (int j = 0; j < 8; ++j) o[j] = f2bf(src[(size_t)(k0 + j) * 512 + n]);
  *(uint4*)(dst + (size_t)t * 8) = *(const uint4*)o;
}

// ---------------------------------------------------------------------------
// transpose + f32->bf16 (GRU weights, [n][k] flat layout)
// ---------------------------------------------------------------------------
__global__ void transpose_f2b(const float* __restrict__ src, unsigned short* __restrict__ dst,
                              int R, int C) {
  __shared__ float t[32][33];
  int c0 = blockIdx.x * 32, r0 = blockIdx.y * 32;
  int tx = threadIdx.x, ty = threadIdx.y;  // 32 x 8
#pragma unroll
  for (int i = 0; i < 32; i += 8) t[ty + i][tx] = src[(size_t)(r0 + ty + i) * C + c0 + tx];
  __syncthreads();
#pragma unroll
  for (int i = 0; i < 32; i += 8) dst[(size_t)(c0 + ty + i) * R + r0 + tx] = f2bf(t[tx][ty + i]);
}

// ---------------------------------------------------------------------------
// obs embed: y = leaky(LN(xs @ W + b)) (f32 in, bf16 out), one wave per row
// ---------------------------------------------------------------------------
__global__ __launch_bounds__(256) void obs_embed(
    const float* __restrict__ xs, const float* __restrict__ W,
    const float* __restrict__ bias, const float* __restrict__ gam,
    const float* __restrict__ bet, unsigned short* __restrict__ Y) {
  __shared__ float Wl[4096];
  const int tid = threadIdx.x, lane = tid & 63, wv = tid >> 6;
#pragma unroll
  for (int i = 0; i < 16; ++i) Wl[i * 256 + tid] = W[i * 256 + tid];
  __syncthreads();
  size_t row = (size_t)blockIdx.x * 4 + wv;
  float xf[8];
  {
    const float* xp = xs + row * 8;
#pragma unroll
    for (int k = 0; k < 8; ++k) xf[k] = xp[k];
  }
  int n0 = lane * 8;
  float a[8];
#pragma unroll
  for (int j = 0; j < 8; ++j) a[j] = bias[n0 + j];
#pragma unroll
  for (int k = 0; k < 8; ++k)
#pragma unroll
    for (int j = 0; j < 8; ++j) a[j] += xf[k] * Wl[k * 512 + n0 + j];
  float s1 = 0.f, s2 = 0.f;
#pragma unroll
  for (int j = 0; j < 8; ++j) { s1 += a[j]; s2 += a[j] * a[j]; }
#pragma unroll
  for (int off = 1; off < 64; off <<= 1) { s1 += __shfl_xor(s1, off); s2 += __shfl_xor(s2, off); }
  float mean = s1 * (1.f / 512.f);
  float rstd = rsqrtf(s2 * (1.f / 512.f) - mean * mean + 1e-5f);
  unsigned short o[8] __attribute__((aligned(16)));
#pragma unroll
  for (int j = 0; j < 8; ++j) {
    float v = (a[j] - mean) * rstd * gam[n0 + j] + bet[n0 + j];
    v = v > 0.f ? v : 0.01f * v;
    o[j] = f2bf(v);
  }
  *(uint4*)(Y + row * 512 + n0) = *(const uint4*)o;
}

// ---------------------------------------------------------------------------
// ODE megakernel, M=64, 512 thr, 8 waves; wave owns M64 x N64
// (nt = 4*wv..4*wv+3). A (64x512) in tiled LDS; B streams global->VGPR dbuf.
// Params in LDS Psu as packed u32 (broadcast reads).
// ---------------------------------------------------------------------------

// element (row, n) address in tiled A (ushort index), row < 64
static __device__ __forceinline__ int a_addr(int row, int n) {
  return (((row >> 4) * 16 + (n >> 5)) * 4 + ((n >> 3) & 3)) * 128 + (row & 15) * 8 + (n & 7);
}

static __device__ __forceinline__ void bload(const unsigned short* __restrict__ Wt, int kk,
                                             int wvoff, bf16x8 (&b)[4]) {
  const unsigned short* p = Wt + (size_t)kk * 16384 + wvoff;
#pragma unroll
  for (int j = 0; j < 4; ++j) b[j] = *(const bf16x8*)(p + j * 512);
}

// acc initialized to bias (splat) -> bias-add pass and zero-init both free.
// a-frags chunked 2 at a time (8 VGPRs, not 16) for the reg cap.
// bb must hold Wt slabs {0,1} on entry; holds Wnext slabs {0,1} on exit.
static __device__ __forceinline__ void gemmS(const unsigned short* __restrict__ Wt,
                                             const unsigned short* __restrict__ Wnext,
                                             const unsigned short* As, int wvoff, int lane,
                                             const float (&bias)[4],
                                             bf16x8 (&bb)[2][4], floatx4 (&acc)[4][4]) {
#pragma unroll
  for (int mi = 0; mi < 4; ++mi)
#pragma unroll
    for (int j = 0; j < 4; ++j)
      acc[mi][j] = (floatx4){bias[j], bias[j], bias[j], bias[j]};
#pragma unroll 2
  for (int kk = 0; kk < 16; ++kk) {  // unroll 2 (dbuf parity), NOT full (R5-R8)
#pragma unroll
    for (int mh = 0; mh < 2; ++mh) {  // a-frag chunking: 2 frags in flight
      bf16x8 a0 = *(const bf16x8*)&As[((2 * mh) * 16 + kk) * 512 + lane * 8];
      bf16x8 a1 = *(const bf16x8*)&As[((2 * mh + 1) * 16 + kk) * 512 + lane * 8];
#pragma unroll
      for (int j = 0; j < 4; ++j) {
        acc[2 * mh][j] =
            __builtin_amdgcn_mfma_f32_16x16x32_bf16(a0, bb[kk & 1][j], acc[2 * mh][j], 0, 0, 0);
        acc[2 * mh + 1][j] =
            __builtin_amdgcn_mfma_f32_16x16x32_bf16(a1, bb[kk & 1][j], acc[2 * mh + 1][j], 0, 0, 0);
      }
    }
    // refill the just-consumed slot: kk+2 of this weight, or next weight's 0/1
    if (kk < 14) bload(Wt, kk + 2, wvoff, bb[kk & 1]);
    else bload(Wnext, kk - 14, wvoff, bb[kk & 1]);
  }
}

// LN + leaky epilogue; 8-wave reduction; gamma/beta read transiently from
// LDS Psu (wave-broadcast, free): gm = gmHi? hi:lo of word wA; bt likewise
// of word wB. All selector args are literals at call sites (folds inline).
static __device__ __forceinline__ void ln_epi(floatx4 (&acc)[4][4], unsigned short* As,
                                              const unsigned int* Psu, int wA, bool gmHi,
                                              int wB, bool btHi,
                                              int wv, int lane, int tid,
                                              float2* red, float* stat) {
  const int ml = lane & 15, qd = lane >> 4;
#pragma unroll
  for (int mi = 0; mi < 4; ++mi)
#pragma unroll
    for (int r = 0; r < 4; ++r) {
      float s1 = 0.f, s2 = 0.f;
#pragma unroll
      for (int j = 0; j < 4; ++j) { float x = acc[mi][j][r]; s1 += x; s2 += x * x; }
      s1 = row16_sum(s1);
      s2 = row16_sum(s2);
      if (ml == 15) red[(mi * 16 + 4 * qd + r) * 8 + wv] = make_float2(s1, s2);
    }
  barrier_lds();  // red visible; all waves past their As a-frag reads
  if (tid < 64) {
    float S1 = 0.f, S2 = 0.f;
#pragma unroll
    for (int w = 0; w < 8; ++w) { float2 v = red[tid * 8 + w]; S1 += v.x; S2 += v.y; }
    float mean = S1 * (1.f / 512.f);
    float var = S2 * (1.f / 512.f) - mean * mean;
    stat[tid * 2] = mean;
    stat[tid * 2 + 1] = rsqrtf(var + 1e-5f);
  }
  barrier_lds();
  float gm[4], bt[4];
#pragma unroll
  for (int j = 0; j < 4; ++j) {
    int n = (4 * wv + j) * 16 + ml;
    unsigned int a = Psu[wA * 512 + n];
    unsigned int b = Psu[wB * 512 + n];
    gm[j] = gmHi ? hi_bf(a) : lo_bf(a);
    bt[j] = btHi ? hi_bf(b) : lo_bf(b);
  }
#pragma unroll
  for (int mi = 0; mi < 4; ++mi) {
    float mean[4], rstd[4];
#pragma unroll
    for (int r = 0; r < 4; ++r) {
      int row = mi * 16 + 4 * qd + r;
      mean[r] = stat[row * 2];
      rstd[r] = stat[row * 2 + 1];
    }
#pragma unroll
    for (int j = 0; j < 4; ++j) {
      int n = (4 * wv + j) * 16 + ml;
#pragma unroll
      for (int r = 0; r < 4; ++r) {
        float x = (acc[mi][j][r] - mean[r]) * (rstd[r] * gm[j]) + bt[j];
        x = x > 0.f ? x : 0.01f * x;
        As[a_addr(mi * 16 + 4 * qd + r, n)] = f2bf(x);
      }
    }
  }
  barrier_lds();  // As writes visible
}

// RK4 stage: kv = acc (bout folded into acc init); h fp32 regs; ksum packed
// bf16 pairs in LDS Ks (per-thread slots, no extra barriers); writes y into
// As; final stage also writes h_ode to Yb.
static __device__ __forceinline__ void stage_epi(floatx4 (&acc)[4][4], float (&h)[4][4][4],
                                                 unsigned int* Ks, unsigned short* As,
                                                 unsigned short* Yb, size_t m0,
                                                 int stg, bool last, int wv, int lane) {
  const int ml = lane & 15, qd = lane >> 4;
  barrier_lds();  // K-loop has no barriers: ensure all waves done reading As
#pragma unroll
  for (int mi = 0; mi < 4; ++mi)
#pragma unroll
    for (int j = 0; j < 4; ++j) {
      int n = (4 * wv + j) * 16 + ml;
#pragma unroll
      for (int rp = 0; rp < 2; ++rp) {
        int kidx = (mi * 8 + qd * 2 + rp) * KSP + n;
        float kv0 = acc[mi][j][2 * rp];
        float kv1 = acc[mi][j][2 * rp + 1];
        unsigned int pk = (stg != 0) ? Ks[kidx] : 0u;
        float s0 = bf2f((unsigned short)(pk & 0xffffu));
        float s1 = bf2f((unsigned short)(pk >> 16));
        float h0 = h[mi][j][2 * rp], h1 = h[mi][j][2 * rp + 1];
        float y0, y1;
        if (stg == 0)      { s0 = kv0;        s1 = kv1;        y0 = h0 + 0.125f * kv0; y1 = h1 + 0.125f * kv1; }
        else if (stg == 1) { s0 += 2.f * kv0; s1 += 2.f * kv1; y0 = h0 + 0.125f * kv0; y1 = h1 + 0.125f * kv1; }
        else if (stg == 2) { s0 += 2.f * kv0; s1 += 2.f * kv1; y0 = h0 + 0.25f * kv0;  y1 = h1 + 0.25f * kv1; }
        else {
          h0 += (1.f / 24.f) * (s0 + kv0);  // dt/6, dt=0.25
          h1 += (1.f / 24.f) * (s1 + kv1);
          h[mi][j][2 * rp] = h0; h[mi][j][2 * rp + 1] = h1;
          y0 = h0; y1 = h1;
        }
        if (stg != 3) Ks[kidx] = (unsigned int)f2bf(s0) | ((unsigned int)f2bf(s1) << 16);
        int row = mi * 16 + 4 * qd + 2 * rp;
        As[a_addr(row, n)] = f2bf(y0);
        As[a_addr(row + 1, n)] = f2bf(y1);
        if (last && stg == 3) {
          Yb[(m0 + row) * 512 + n] = f2bf(y0);
          Yb[(m0 + row + 1) * 512 + n] = f2bf(y1);
        }
      }
    }
  barrier_lds();  // As writes visible
}

__global__ __launch_bounds__(512) void ode_mega(
    unsigned short* Yb, const unsigned short* __restrict__ W1t,
    const unsigned short* __restrict__ W2t, const unsigned short* __restrict__ Wot,
    const float* __restrict__ b1, const float* __restrict__ tr, const float* __restrict__ g1,
    const float* __restrict__ be1, const float* __restrict__ b2, const float* __restrict__ g2,
    const float* __restrict__ be2, const float* __restrict__ bo) {
  __shared__ __align__(16) unsigned short As[32768];  // 64KB tiled A (64 rows)
  __shared__ __align__(16) unsigned int Psu[2048];    // 8KB packed params
  __shared__ float2 red[512];                         // 4KB: 64 rows x 8 waves
  __shared__ float stat[128];                         // 512B
  __shared__ __align__(16) unsigned int Ks[32 * KSP]; // 66KB RK4 ksum
  // total ~142.6KB <= 160KB; 1 block/CU (reg-law pinned)

  const int tid = threadIdx.x;
  const int lane = tid & 63;
  const int wv = tid >> 6;  // 0..7
  const int ml = lane & 15;
  const int qd = lane >> 4;
  const size_t m0 = (size_t)blockIdx.x * 64;
  const int wvoff = wv * 2048 + lane * 8;  // (4wv)*512 + lane*8

  // start weight prefetch immediately
  bf16x8 bb[2][4];
  bload(W1t, 0, wvoff, bb[0]);
  bload(W1t, 1, wvoff, bb[1]);

  // stage packed params: Psu[v*512+n], v = {(b1|tr),(g1|be1),(b2|g2),(be2|bo)}
  Psu[0 * 512 + tid] = pk2(b1[tid], tr[tid]);
  Psu[1 * 512 + tid] = pk2(g1[tid], be1[tid]);
  Psu[2 * 512 + tid] = pk2(b2[tid], g2[tid]);
  Psu[3 * 512 + tid] = pk2(be2[tid], bo[tid]);

  // stage As: thread owns row r = tid>>3, chunks c = (tid&7) + i*8, i=0..7
  {
    int r = tid >> 3;       // 0..63
    int c0 = tid & 7;
#pragma unroll
    for (int i = 0; i < 8; ++i) {
      int c = c0 + i * 8;   // 0..63
      uint4 v = *(const uint4*)(Yb + (m0 + r) * 512 + c * 8);
      int dst = (((r >> 4) * 16 + (c >> 2)) * 4 + (c & 3)) * 128 + (r & 15) * 8;
      *(uint4*)(As + dst) = v;
    }
  }
  barrier_lds();

  float h[4][4][4];  // fp32 ODE state, MFMA C-layout (64 elems/thread)
#pragma unroll
  for (int mi = 0; mi < 4; ++mi)
#pragma unroll
    for (int j = 0; j < 4; ++j) {
      int n = (4 * wv + j) * 16 + ml;
#pragma unroll
      for (int r = 0; r < 4; ++r) h[mi][j][r] = bf2f(As[a_addr(mi * 16 + 4 * qd + r, n)]);
    }

  for (int e = 0; e < 16; ++e) {  // 4 RK4 steps x 4 stages
    int stg = e & 3;
    float tval = 0.25f * (float)(e >> 2) + ((stg == 3) ? 0.25f : (stg ? 0.125f : 0.f));
    floatx4 acc[4][4];
    float bias[4];

#pragma unroll
    for (int j = 0; j < 4; ++j) {  // layer-1 bias (time row folded, LDS bcast)
      unsigned int p0 = Psu[0 * 512 + (4 * wv + j) * 16 + ml];
      bias[j] = lo_bf(p0) + tval * hi_bf(p0);
    }
    gemmS(W1t, W2t, As, wvoff, lane, bias, bb, acc);
    ln_epi(acc, As, Psu, 1, false, 1, true, wv, lane, tid, red, stat);

#pragma unroll
    for (int j = 0; j < 4; ++j)  // layer-2 bias
      bias[j] = lo_bf(Psu[2 * 512 + (4 * wv + j) * 16 + ml]);
    gemmS(W2t, Wot, As, wvoff, lane, bias, bb, acc);
    ln_epi(acc, As, Psu, 2, true, 3, false, wv, lane, tid, red, stat);

#pragma unroll
    for (int j = 0; j < 4; ++j)  // out-layer bias (bo)
      bias[j] = hi_bf(Psu[3 * 512 + (4 * wv + j) * 16 + ml]);
    gemmS(Wot, W1t, As, wvoff, lane, bias, bb, acc);  // preloads next eval's W1
    stage_epi(acc, h, Ks, As, Yb, m0, stg, e == 15, wv, lane);
  }
}

// ---------------------------------------------------------------------------
// GRU step: gi = y_t @ W_ih, gh = h_prev @ W_hh, gates.
// grid (32, 8): 32 rows x 64 gate-cols per block, 4 waves.
// ---------------------------------------------------------------------------
__global__ __launch_bounds__(256) void gru_step(
    const unsigned short* __restrict__ Yt, const float* __restrict__ hprev,
    float* __restrict__ hnew, const unsigned short* __restrict__ Wiht,
    const unsigned short* __restrict__ Whht, const float* __restrict__ bih,
    const float* __restrict__ bhh) {
  __shared__ __align__(16) unsigned short Ay[32 * BP];
  __shared__ __align__(16) unsigned short Ah[32 * BP];
  __shared__ __align__(16) unsigned short Bg[6 * 64 * BP];
  const int tid = threadIdx.x, lane = tid & 63, wv = tid >> 6;
  const int ml = lane & 15, qd = lane >> 4;
  const int m0 = blockIdx.x * 32;
  const int j0 = blockIdx.y * 64;

  floatx4 acc[2][6];
#pragma unroll
  for (int mi = 0; mi < 2; ++mi)
#pragma unroll
    for (int g = 0; g < 6; ++g) acc[mi][g] = 0.f;

  for (int kk = 0; kk < 16; ++kk) {
    __syncthreads();
#pragma unroll
    for (int c = 0; c < 7; ++c) {
      int id = c * 256 + tid;
      if (id < 128) {
        int r = id >> 2, kc = id & 3;
        *(uint4*)(Ay + r * BP + kc * 8) =
            *(const uint4*)(Yt + (size_t)(m0 + r) * 512 + kk * 32 + kc * 8);
      } else if (id < 256) {
        int id2 = id - 128;
        int r = id2 >> 2, kc = id2 & 3;
        const float* s = hprev + (size_t)(m0 + r) * 512 + kk * 32 + kc * 8;
        unsigned short o[8] __attribute__((aligned(16)));
#pragma unroll
        for (int j = 0; j < 8; ++j) o[j] = f2bf(s[j]);
        *(uint4*)(Ah + r * BP + kc * 8) = *(const uint4*)o;
      } else {
        int id2 = id - 256;
        int g = id2 >> 8;
        int rem = id2 & 255;
        int r = rem >> 2, kc = rem & 3;
        const unsigned short* mat = (g < 3) ? Wiht : Whht;
        int gate = (g < 3) ? g : (g - 3);
        *(uint4*)(Bg + g * (64 * BP) + r * BP + kc * 8) =
            *(const uint4*)(mat + (size_t)(gate * 512 + j0 + r) * 512 + kk * 32 + kc * 8);
      }
    }
    __syncthreads();
    bf16x8 ay[2], ah[2];
#pragma unroll
    for (int mi = 0; mi < 2; ++mi) {
      ay[mi] = *(const bf16x8*)&Ay[(16 * mi + ml) * BP + qd * 8];
      ah[mi] = *(const bf16x8*)&Ah[(16 * mi + ml) * BP + qd * 8];
    }
#pragma unroll
    for (int g = 0; g < 6; ++g) {
      bf16x8 b = *(const bf16x8*)&Bg[g * (64 * BP) + (16 * wv + ml) * BP + qd * 8];
#pragma unroll
      for (int mi = 0; mi < 2; ++mi)
        acc[mi][g] = __builtin_amdgcn_mfma_f32_16x16x32_bf16((g < 3) ? ay[mi] : ah[mi], b,
                                                             acc[mi][g], 0, 0, 0);
    }
  }
  int j = j0 + 16 * wv + ml;
  float bi_r = bih[j], bi_z = bih[512 + j], bi_n = bih[1024 + j];
  float bh_r = bhh[j], bh_z = bhh[512 + j], bh_n = bhh[1024 + j];
#pragma unroll
  for (int mi = 0; mi < 2; ++mi)
#pragma unroll
    for (int r = 0; r < 4; ++r) {
      size_t row = (size_t)(m0 + 16 * mi + 4 * qd + r);
      float rg = acc[mi][0][r] + bi_r + acc[mi][3][r] + bh_r;
      rg = 1.f / (1.f + __expf(-rg));
      float zg = acc[mi][1][r] + bi_z + acc[mi][4][r] + bh_z;
      zg = 1.f / (1.f + __expf(-zg));
      float ng = tanhf(acc[mi][2][r] + bi_n + rg * (acc[mi][5][r] + bh_n));
      float hp = hprev[row * 512 + j];
      hnew[row * 512 + j] = (1.f - zg) * ng + zg * hp;
    }
}

__global__ void zero_h(float* hf) {
  int i = blockIdx.x * 256 + threadIdx.x;
  hf[i] = 0.f;
}

// ---------------------------------------------------------------------------
extern "C" void kernel_launch(void* const* d_in, const int* in_sizes, int n_in,
                              void* d_out, int out_size, void* d_ws, size_t ws_size,
                              hipStream_t stream) {
  (void)in_sizes; (void)n_in; (void)out_size; (void)ws_size;
  const float* xs    = (const float*)d_in[0];
  const float* obsW  = (const float*)d_in[1];
  const float* obsb  = (const float*)d_in[2];
  const float* obsg  = (const float*)d_in[3];
  const float* obsbe = (const float*)d_in[4];
  const float* W1    = (const float*)d_in[5];
  const float* b1    = (const float*)d_in[6];
  const float* g1    = (const float*)d_in[7];
  const float* be1   = (const float*)d_in[8];
  const float* W2    = (const float*)d_in[9];
  const float* b2    = (const float*)d_in[10];
  const float* g2    = (const float*)d_in[11];
  const float* be2   = (const float*)d_in[12];
  const float* Wo    = (const float*)d_in[13];
  const float* bo    = (const float*)d_in[14];
  const float* Wih   = (const float*)d_in[15];
  const float* bih   = (const float*)d_in[16];
  const float* Whh   = (const float*)d_in[17];
  const float* bhh   = (const float*)d_in[18];

  char* p = (char*)d_ws;
  auto take = [&](size_t bytes) { char* q = p; p += (bytes + 255) & ~(size_t)255; return q; };
  unsigned short* W1t  = (unsigned short*)take((size_t)512 * 512 * 2);
  unsigned short* W2t  = (unsigned short*)take((size_t)512 * 512 * 2);
  unsigned short* Wot  = (unsigned short*)take((size_t)512 * 512 * 2);
  unsigned short* Wiht = (unsigned short*)take((size_t)1536 * 512 * 2);
  unsigned short* Whht = (unsigned short*)take((size_t)1536 * 512 * 2);
  float* hf0 = (float*)take((size_t)1024 * 512 * 4);
  float* hf1 = (float*)take((size_t)1024 * 512 * 4);
  unsigned short* Yb = (unsigned short*)take((size_t)65536 * 512 * 2);

  dim3 tb(32, 8);
  tile_weight<<<128, 256, 0, stream>>>(W1, W1t);  // first 512 of 513 rows
  tile_weight<<<128, 256, 0, stream>>>(W2, W2t);
  tile_weight<<<128, 256, 0, stream>>>(Wo, Wot);
  transpose_f2b<<<dim3(48, 16), tb, 0, stream>>>(Wih, Wiht, 512, 1536);
  transpose_f2b<<<dim3(48, 16), tb, 0, stream>>>(Whh, Whht, 512, 1536);

  obs_embed<<<16384, 256, 0, stream>>>(xs, obsW, obsb, obsg, obsbe, Yb);

  // tr = W1 row 512 (time row), folded into layer-1 bias per eval.
  ode_mega<<<1024, 512, 0, stream>>>(Yb, W1t, W2t, Wot, b1, W1 + 512 * 512, g1, be1, b2, g2,
                                     be2, bo);

  zero_h<<<2048, 256, 0, stream>>>(hf0);
  float* hf[2] = {hf0, hf1};
  for (int t = 0; t < 64; ++t) {
    int s = t & 1, d = s ^ 1;
    float* hn = (t == 63) ? (float*)d_out : hf[d];
    gru_step<<<dim3(32, 8), 256, 0, stream>>>(Yb + (size_t)t * 1024 * 512, hf[s], hn, Wiht, Whht,
                                              bih, bhh);
  }
}

// Round 8
// 3280.465 us; speedup vs baseline: 1.1604x; 1.0337x over previous
//
#include <hip/hip_runtime.h>
#include <stdint.h>

// ---------------------------------------------------------------------------
// ODE-RNN encoder, f32 I/O, bf16 MFMA internals.
// R25 = R24 + MFMA OPERAND SWAP: mfma(bb, a, acc) computes Y^T, so each lane
// holds 4 CONSECUTIVE n at one batch row (acc[r] = Y[mi*16+ml][nb+qd*4+r]).
// Works because A/B operands share the same per-lane layout (k-major,
// row/col = lane&15) and both our tiles are already stored that way.
// Epilogue restructure enabled by the swap:
//  * LN row-sum: register-local 16-value sum + 2 shfl_xor (was 32 serial
//    DPP chains); per-wave stats from red (serial tid<64 stage + 1 barrier
//    deleted); stats/thread 16 -> 4 pairs.
//  * All As/Yb writes vectorized: ds_write_b64 (192 -> 48 LDS writes/eval).
//  * Params as f32 LDS arrays, read ds_read_b128 (bias/gm/bt quads).
//  * Ks stride 257 (bank-safe), red stride 9 (8-way -> 2-way).
// R24 post-mortem: spill fix confirmed (510->73MB residual, VGPR=128 at cap),
// ode 2267us, MfmaUtil 35.2% = MFMA floor 29.8K of 85K cyc/eval; epilogue
// ~55K is the remaining target; SQ_LDS_BANK_CONFLICT 6.9e7.
// Laws: arch-VGPR cap = 65536/threads, AGPR separate (R17-R23); occupancy
// pinned 1 block/CU @512thr; M=64 balances vmem 25.6K vs MFMA 29.8K (R22);
// M=16 kills B amortization (R20); no global_load_lds (R12/13); 2-slab B
// dbuf; no global RK4 state (R15); GRU simple (R15/R16).
// ---------------------------------------------------------------------------

typedef __bf16 bf16x8 __attribute__((ext_vector_type(8)));
typedef float floatx4 __attribute__((ext_vector_type(4)));

#define BP 40    // gru padded B row (ushorts)
#define KSR 257  // Ks row stride (uints), row = batch row
#define REDW 9   // red row stride (float2)

static __device__ __forceinline__ float bf2f(unsigned short u) {
  union { unsigned int u32; float f; } c;
  c.u32 = ((unsigned int)u) << 16;
  return c.f;
}
static __device__ __forceinline__ unsigned short f2bf(float f) {
  union { __bf16 h; unsigned short u; } c;
  c.h = (__bf16)f;  // RNE
  return c.u;
}
static __device__ __forceinline__ unsigned int pk2(float a, float b) {
  return (unsigned int)f2bf(a) | ((unsigned int)f2bf(b) << 16);
}

// LDS-only barrier: does NOT drain vmcnt, so global prefetches stay in flight.
static __device__ __forceinline__ void barrier_lds() {
  __asm__ volatile("s_waitcnt lgkmcnt(0)\n\ts_barrier" ::: "memory");
}

// ---------------------------------------------------------------------------
// tile_weight: W (K=512 x N=512, f32 row-major) -> bf16 tiled
// [kk(16)][nt(32)][qd(4)][ml(16)][8]; element (kk,nt,qd,ml,j) = W[kk*32+qd*8+j][nt*16+ml]
// ---------------------------------------------------------------------------
__global__ void tile_weight(const float* __restrict__ src, unsigned short* __restrict__ dst) {
  int t = blockIdx.x * 256 + threadIdx.x;  // 0..32767
  int ml = t & 15, qd = (t >> 4) & 3;
  int nt = (t >> 6) & 31, kk = t >> 11;
  int n = nt * 16 + ml;
  int k0 = kk * 32 + qd * 8;
  unsigned short o[8] __attribute__((aligned(16)));
#pragma unroll
  for (int j = 0; j < 8; ++j) o[j] = f2bf(src[(size_t)(k0 + j) * 512 + n]);
  *(uint4*)(dst + (size_t)t * 8) = *(const uint4*)o;
}

// ---------------------------------------------------------------------------
// transpose + f32->bf16 (GRU weights, [n][k] flat layout)
// ---------------------------------------------------------------------------
__global__ void transpose_f2b(const float* __restrict__ src, unsigned short* __restrict__ dst,
                              int R, int C) {
  __shared__ float t[32][33];
  int c0 = blockIdx.x * 32, r0 = blockIdx.y * 32;
  int tx = threadIdx.x, ty = threadIdx.y;  // 32 x 8
#pragma unroll
  for (int i = 0; i < 32; i += 8) t[ty + i][tx] = src[(size_t)(r0 + ty + i) * C + c0 + tx];
  __syncthreads();
#pragma unroll
  for (int i = 0; i < 32; i += 8) dst[(size_t)(c0 + ty + i) * R + r0 + tx] = f2bf(t[tx][ty + i]);
}

// ---------------------------------------------------------------------------
// obs embed: y = leaky(LN(xs @ W + b)) (f32 in, bf16 out), one wave per row
// ---------------------------------------------------------------------------
__global__ __launch_bounds__(256) void obs_embed(
    const float* __restrict__ xs, const float* __restrict__ W,
    const float* __restrict__ bias, const float* __restrict__ gam,
    const float* __restrict__ bet, unsigned short* __restrict__ Y) {
  __shared__ float Wl[4096];
  const int tid = threadIdx.x, lane = tid & 63, wv = tid >> 6;
#pragma unroll
  for (int i = 0; i < 16; ++i) Wl[i * 256 + tid] = W[i * 256 + tid];
  __syncthreads();
  size_t row = (size_t)blockIdx.x * 4 + wv;
  float xf[8];
  {
    const float* xp = xs + row * 8;
#pragma unroll
    for (int k = 0; k < 8; ++k) xf[k] = xp[k];
  }
  int n0 = lane * 8;
  float a[8];
#pragma unroll
  for (int j = 0; j < 8; ++j) a[j] = bias[n0 + j];
#pragma unroll
  for (int k = 0; k < 8; ++k)
#pragma unroll
    for (int j = 0; j < 8; ++j) a[j] += xf[k] * Wl[k * 512 + n0 + j];
  float s1 = 0.f, s2 = 0.f;
#pragma unroll
  for (int j = 0; j < 8; ++j) { s1 += a[j]; s2 += a[j] * a[j]; }
#pragma unroll
  for (int off = 1; off < 64; off <<= 1) { s1 += __shfl_xor(s1, off); s2 += __shfl_xor(s2, off); }
  float mean = s1 * (1.f / 512.f);
  float rstd = rsqrtf(s2 * (1.f / 512.f) - mean * mean + 1e-5f);
  unsigned short o[8] __attribute__((aligned(16)));
#pragma unroll
  for (int j = 0; j < 8; ++j) {
    float v = (a[j] - mean) * rstd * gam[n0 + j] + bet[n0 + j];
    v = v > 0.f ? v : 0.01f * v;
    o[j] = f2bf(v);
  }
  *(uint4*)(Y + row * 512 + n0) = *(const uint4*)o;
}

// ---------------------------------------------------------------------------
// ODE megakernel, M=64, 512 thr, 8 waves; wave owns M64 x N64
// (nt = 4*wv..4*wv+3). A (64x512) in tiled LDS; B streams global->VGPR dbuf.
// Swapped MFMA: acc[mi][j][r] = Y[mi*16+ml][(4wv+j)*16 + qd*4 + r].
// ---------------------------------------------------------------------------

// element (row, n) address in tiled A (ushort index), row < 64
static __device__ __forceinline__ int a_addr(int row, int n) {
  return (((row >> 4) * 16 + (n >> 5)) * 4 + ((n >> 3) & 3)) * 128 + (row & 15) * 8 + (n & 7);
}

static __device__ __forceinline__ void bload(const unsigned short* __restrict__ Wt, int kk,
                                             int wvoff, bf16x8 (&b)[4]) {
  const unsigned short* p = Wt + (size_t)kk * 16384 + wvoff;
#pragma unroll
  for (int j = 0; j < 4; ++j) b[j] = *(const bf16x8*)(p + j * 512);
}

// acc initialized to per-n bias quad (r-component = n offset) -> bias-add
// pass and zero-init both free. a-frags chunked 2 at a time (reg cap).
// bb must hold Wt slabs {0,1} on entry; holds Wnext slabs {0,1} on exit.
static __device__ __forceinline__ void gemmS(const unsigned short* __restrict__ Wt,
                                             const unsigned short* __restrict__ Wnext,
                                             const unsigned short* As, int wvoff, int lane,
                                             const floatx4 (&bias)[4],
                                             bf16x8 (&bb)[2][4], floatx4 (&acc)[4][4]) {
#pragma unroll
  for (int mi = 0; mi < 4; ++mi)
#pragma unroll
    for (int j = 0; j < 4; ++j) acc[mi][j] = bias[j];
#pragma unroll 2
  for (int kk = 0; kk < 16; ++kk) {  // unroll 2 (dbuf parity), NOT full (R5-R8)
#pragma unroll
    for (int mh = 0; mh < 2; ++mh) {  // a-frag chunking: 2 frags in flight
      bf16x8 a0 = *(const bf16x8*)&As[((2 * mh) * 16 + kk) * 512 + lane * 8];
      bf16x8 a1 = *(const bf16x8*)&As[((2 * mh + 1) * 16 + kk) * 512 + lane * 8];
#pragma unroll
      for (int j = 0; j < 4; ++j) {
        // SWAPPED operands: D = W^T . X^T = Y^T
        acc[2 * mh][j] =
            __builtin_amdgcn_mfma_f32_16x16x32_bf16(bb[kk & 1][j], a0, acc[2 * mh][j], 0, 0, 0);
        acc[2 * mh + 1][j] =
            __builtin_amdgcn_mfma_f32_16x16x32_bf16(bb[kk & 1][j], a1, acc[2 * mh + 1][j], 0, 0, 0);
      }
    }
    // refill the just-consumed slot: kk+2 of this weight, or next weight's 0/1
    if (kk < 14) bload(Wt, kk + 2, wvoff, bb[kk & 1]);
    else bload(Wnext, kk - 14, wvoff, bb[kk & 1]);
  }
}

// LN + leaky epilogue (swapped layout): register-local row sums + 2 shfl_xor,
// per-wave stats, b64 As writes. Pg/Pb = f32 gamma/beta arrays in LDS.
static __device__ __forceinline__ void ln_epi(floatx4 (&acc)[4][4], unsigned short* As,
                                              const float* Pg, const float* Pb,
                                              int wv, int lane, float2* red) {
  const int ml = lane & 15, qd = lane >> 4;
#pragma unroll
  for (int mi = 0; mi < 4; ++mi) {
    float s1 = 0.f, s2 = 0.f;
#pragma unroll
    for (int j = 0; j < 4; ++j)
#pragma unroll
      for (int r = 0; r < 4; ++r) { float x = acc[mi][j][r]; s1 += x; s2 += x * x; }
    s1 += __shfl_xor(s1, 16); s2 += __shfl_xor(s2, 16);
    s1 += __shfl_xor(s1, 32); s2 += __shfl_xor(s2, 32);
    if (qd == 0) red[(mi * 16 + ml) * REDW + wv] = make_float2(s1, s2);
  }
  barrier_lds();  // red visible; all waves past their As a-frag reads
  float mean[4], rstd[4];
#pragma unroll
  for (int mi = 0; mi < 4; ++mi) {
    float S1 = 0.f, S2 = 0.f;
#pragma unroll
    for (int w = 0; w < 8; ++w) {
      float2 v = red[(mi * 16 + ml) * REDW + w];
      S1 += v.x; S2 += v.y;
    }
    float m = S1 * (1.f / 512.f);
    mean[mi] = m;
    rstd[mi] = rsqrtf(S2 * (1.f / 512.f) - m * m + 1e-5f);
  }
#pragma unroll
  for (int j = 0; j < 4; ++j) {
    int nb = (4 * wv + j) * 16 + qd * 4;
    floatx4 gm = *(const floatx4*)&Pg[nb];
    floatx4 bt = *(const floatx4*)&Pb[nb];
#pragma unroll
    for (int mi = 0; mi < 4; ++mi) {
      float x0 = (acc[mi][j][0] - mean[mi]) * rstd[mi] * gm[0] + bt[0];
      float x1 = (acc[mi][j][1] - mean[mi]) * rstd[mi] * gm[1] + bt[1];
      float x2 = (acc[mi][j][2] - mean[mi]) * rstd[mi] * gm[2] + bt[2];
      float x3 = (acc[mi][j][3] - mean[mi]) * rstd[mi] * gm[3] + bt[3];
      x0 = x0 > 0.f ? x0 : 0.01f * x0;
      x1 = x1 > 0.f ? x1 : 0.01f * x1;
      x2 = x2 > 0.f ? x2 : 0.01f * x2;
      x3 = x3 > 0.f ? x3 : 0.01f * x3;
      uint2 o = make_uint2(pk2(x0, x1), pk2(x2, x3));
      *(uint2*)(As + a_addr(mi * 16 + ml, nb)) = o;  // 4 consecutive n: b64
    }
  }
  barrier_lds();  // As writes visible
}

// RK4 stage (swapped layout): kv = acc (bout folded into init); h fp32 regs;
// ksum packed bf16 n-pairs in LDS Ks (per-thread slots); b64 As/Yb writes.
static __device__ __forceinline__ void stage_epi(floatx4 (&acc)[4][4], float (&h)[4][4][4],
                                                 unsigned int* Ks, unsigned short* As,
                                                 unsigned short* Yb, size_t m0,
                                                 int stg, bool last, int wv, int lane) {
  const int ml = lane & 15, qd = lane >> 4;
  barrier_lds();  // K-loop has no barriers: ensure all waves done reading As
#pragma unroll
  for (int mi = 0; mi < 4; ++mi) {
    int rowK = (mi * 16 + ml) * KSR;
#pragma unroll
    for (int j = 0; j < 4; ++j) {
      int nb = (4 * wv + j) * 16 + qd * 4;
      unsigned int yw[2];
#pragma unroll
      for (int p = 0; p < 2; ++p) {
        int kidx = rowK + (4 * wv + j) * 8 + qd * 2 + p;
        float kv0 = acc[mi][j][2 * p];
        float kv1 = acc[mi][j][2 * p + 1];
        unsigned int pk = (stg != 0) ? Ks[kidx] : 0u;
        float s0 = bf2f((unsigned short)(pk & 0xffffu));
        float s1 = bf2f((unsigned short)(pk >> 16));
        float h0 = h[mi][j][2 * p], h1 = h[mi][j][2 * p + 1];
        float y0, y1;
        if (stg == 0)      { s0 = kv0;        s1 = kv1;        y0 = h0 + 0.125f * kv0; y1 = h1 + 0.125f * kv1; }
        else if (stg == 1) { s0 += 2.f * kv0; s1 += 2.f * kv1; y0 = h0 + 0.125f * kv0; y1 = h1 + 0.125f * kv1; }
        else if (stg == 2) { s0 += 2.f * kv0; s1 += 2.f * kv1; y0 = h0 + 0.25f * kv0;  y1 = h1 + 0.25f * kv1; }
        else {
          h0 += (1.f / 24.f) * (s0 + kv0);  // dt/6, dt=0.25
          h1 += (1.f / 24.f) * (s1 + kv1);
          h[mi][j][2 * p] = h0; h[mi][j][2 * p + 1] = h1;
          y0 = h0; y1 = h1;
        }
        if (stg != 3) Ks[kidx] = pk2(s0, s1);
        yw[p] = pk2(y0, y1);
      }
      uint2 o = make_uint2(yw[0], yw[1]);
      *(uint2*)(As + a_addr(mi * 16 + ml, nb)) = o;  // 4 consecutive n: b64
      if (last && stg == 3)
        *(uint2*)(Yb + (m0 + mi * 16 + ml) * 512 + nb) = o;
    }
  }
  barrier_lds();  // As writes visible
}

__global__ __launch_bounds__(512) void ode_mega(
    unsigned short* Yb, const unsigned short* __restrict__ W1t,
    const unsigned short* __restrict__ W2t, const unsigned short* __restrict__ Wot,
    const float* __restrict__ b1, const float* __restrict__ tr, const float* __restrict__ g1,
    const float* __restrict__ be1, const float* __restrict__ b2, const float* __restrict__ g2,
    const float* __restrict__ be2, const float* __restrict__ bo) {
  __shared__ __align__(16) unsigned short As[32768];  // 64KB tiled A (64 rows)
  __shared__ __align__(16) float Pf[8 * 512];         // 16KB f32 params
  __shared__ float2 red[64 * REDW];                   // 4.5KB padded
  __shared__ __align__(16) unsigned int Ks[64 * KSR]; // 65.8KB RK4 ksum
  // total ~148.8KB <= 160KB; 1 block/CU (reg-law pinned)

  const int tid = threadIdx.x;
  const int lane = tid & 63;
  const int wv = tid >> 6;  // 0..7
  const int ml = lane & 15;
  const int qd = lane >> 4;
  const size_t m0 = (size_t)blockIdx.x * 64;
  const int wvoff = wv * 2048 + lane * 8;  // (4wv)*512 + lane*8

  // start weight prefetch immediately
  bf16x8 bb[2][4];
  bload(W1t, 0, wvoff, bb[0]);
  bload(W1t, 1, wvoff, bb[1]);

  // stage f32 params: {b1, tr, g1, be1, b2, g2, be2, bo}
  {
    const float* srcs[8] = {b1, tr, g1, be1, b2, g2, be2, bo};
#pragma unroll
    for (int v = 0; v < 8; ++v) Pf[v * 512 + tid] = srcs[v][tid];
  }

  // stage As: thread owns row r = tid>>3, chunks c = (tid&7) + i*8, i=0..7
  {
    int r = tid >> 3;       // 0..63
    int c0 = tid & 7;
#pragma unroll
    for (int i = 0; i < 8; ++i) {
      int c = c0 + i * 8;   // 0..63
      uint4 v = *(const uint4*)(Yb + (m0 + r) * 512 + c * 8);
      int dst = (((r >> 4) * 16 + (c >> 2)) * 4 + (c & 3)) * 128 + (r & 15) * 8;
      *(uint4*)(As + dst) = v;
    }
  }
  barrier_lds();

  float h[4][4][4];  // fp32 ODE state, swapped layout (64 elems/thread)
#pragma unroll
  for (int mi = 0; mi < 4; ++mi)
#pragma unroll
    for (int j = 0; j < 4; ++j) {
      int nb = (4 * wv + j) * 16 + qd * 4;
      uint2 v = *(const uint2*)(As + a_addr(mi * 16 + ml, nb));
      h[mi][j][0] = bf2f((unsigned short)(v.x & 0xffffu));
      h[mi][j][1] = bf2f((unsigned short)(v.x >> 16));
      h[mi][j][2] = bf2f((unsigned short)(v.y & 0xffffu));
      h[mi][j][3] = bf2f((unsigned short)(v.y >> 16));
    }

  for (int e = 0; e < 16; ++e) {  // 4 RK4 steps x 4 stages
    int stg = e & 3;
    float tval = 0.25f * (float)(e >> 2) + ((stg == 3) ? 0.25f : (stg ? 0.125f : 0.f));
    floatx4 acc[4][4];
    floatx4 bias[4];

#pragma unroll
    for (int j = 0; j < 4; ++j) {  // layer-1 bias quad (time row folded)
      int nb = (4 * wv + j) * 16 + qd * 4;
      floatx4 vb = *(const floatx4*)&Pf[0 * 512 + nb];
      floatx4 vt = *(const floatx4*)&Pf[1 * 512 + nb];
#pragma unroll
      for (int r = 0; r < 4; ++r) bias[j][r] = vb[r] + tval * vt[r];
    }
    gemmS(W1t, W2t, As, wvoff, lane, bias, bb, acc);
    ln_epi(acc, As, Pf + 2 * 512, Pf + 3 * 512, wv, lane, red);

#pragma unroll
    for (int j = 0; j < 4; ++j) {  // layer-2 bias quad
      int nb = (4 * wv + j) * 16 + qd * 4;
      bias[j] = *(const floatx4*)&Pf[4 * 512 + nb];
    }
    gemmS(W2t, Wot, As, wvoff, lane, bias, bb, acc);
    ln_epi(acc, As, Pf + 5 * 512, Pf + 6 * 512, wv, lane, red);

#pragma unroll
    for (int j = 0; j < 4; ++j) {  // out-layer bias quad (bo)
      int nb = (4 * wv + j) * 16 + qd * 4;
      bias[j] = *(const floatx4*)&Pf[7 * 512 + nb];
    }
    gemmS(Wot, W1t, As, wvoff, lane, bias, bb, acc);  // preloads next eval's W1
    stage_epi(acc, h, Ks, As, Yb, m0, stg, e == 15, wv, lane);
  }
}

// ---------------------------------------------------------------------------
// GRU step: gi = y_t @ W_ih, gh = h_prev @ W_hh, gates.
// grid (32, 8): 32 rows x 64 gate-cols per block, 4 waves.
// ---------------------------------------------------------------------------
__global__ __launch_bounds__(256) void gru_step(
    const unsigned short* __restrict__ Yt, const float* __restrict__ hprev,
    float* __restrict__ hnew, const unsigned short* __restrict__ Wiht,
    const unsigned short* __restrict__ Whht, const float* __restrict__ bih,
    const float* __restrict__ bhh) {
  __shared__ __align__(16) unsigned short Ay[32 * BP];
  __shared__ __align__(16) unsigned short Ah[32 * BP];
  __shared__ __align__(16) unsigned short Bg[6 * 64 * BP];
  const int tid = threadIdx.x, lane = tid & 63, wv = tid >> 6;
  const int ml = lane & 15, qd = lane >> 4;
  const int m0 = blockIdx.x * 32;
  const int j0 = blockIdx.y * 64;

  floatx4 acc[2][6];
#pragma unroll
  for (int mi = 0; mi < 2; ++mi)
#pragma unroll
    for (int g = 0; g < 6; ++g) acc[mi][g] = 0.f;

  for (int kk = 0; kk < 16; ++kk) {
    __syncthreads();
#pragma unroll
    for (int c = 0; c < 7; ++c) {
      int id = c * 256 + tid;
      if (id < 128) {
        int r = id >> 2, kc = id & 3;
        *(uint4*)(Ay + r * BP + kc * 8) =
            *(const uint4*)(Yt + (size_t)(m0 + r) * 512 + kk * 32 + kc * 8);
      } else if (id < 256) {
        int id2 = id - 128;
        int r = id2 >> 2, kc = id2 & 3;
        const float* s = hprev + (size_t)(m0 + r) * 512 + kk * 32 + kc * 8;
        unsigned short o[8] __attribute__((aligned(16)));
#pragma unroll
        for (int j = 0; j < 8; ++j) o[j] = f2bf(s[j]);
        *(uint4*)(Ah + r * BP + kc * 8) = *(const uint4*)o;
      } else {
        int id2 = id - 256;
        int g = id2 >> 8;
        int rem = id2 & 255;
        int r = rem >> 2, kc = rem & 3;
        const unsigned short* mat = (g < 3) ? Wiht : Whht;
        int gate = (g < 3) ? g : (g - 3);
        *(uint4*)(Bg + g * (64 * BP) + r * BP + kc * 8) =
            *(const uint4*)(mat + (size_t)(gate * 512 + j0 + r) * 512 + kk * 32 + kc * 8);
      }
    }
    __syncthreads();
    bf16x8 ay[2], ah[2];
#pragma unroll
    for (int mi = 0; mi < 2; ++mi) {
      ay[mi] = *(const bf16x8*)&Ay[(16 * mi + ml) * BP + qd * 8];
      ah[mi] = *(const bf16x8*)&Ah[(16 * mi + ml) * BP + qd * 8];
    }
#pragma unroll
    for (int g = 0; g < 6; ++g) {
      bf16x8 b = *(const bf16x8*)&Bg[g * (64 * BP) + (16 * wv + ml) * BP + qd * 8];
#pragma unroll
      for (int mi = 0; mi < 2; ++mi)
        acc[mi][g] = __builtin_amdgcn_mfma_f32_16x16x32_bf16((g < 3) ? ay[mi] : ah[mi], b,
                                                             acc[mi][g], 0, 0, 0);
    }
  }
  int j = j0 + 16 * wv + ml;
  float bi_r = bih[j], bi_z = bih[512 + j], bi_n = bih[1024 + j];
  float bh_r = bhh[j], bh_z = bhh[512 + j], bh_n = bhh[1024 + j];
#pragma unroll
  for (int mi = 0; mi < 2; ++mi)
#pragma unroll
    for (int r = 0; r < 4; ++r) {
      size_t row = (size_t)(m0 + 16 * mi + 4 * qd + r);
      float rg = acc[mi][0][r] + bi_r + acc[mi][3][r] + bh_r;
      rg = 1.f / (1.f + __expf(-rg));
      float zg = acc[mi][1][r] + bi_z + acc[mi][4][r] + bh_z;
      zg = 1.f / (1.f + __expf(-zg));
      float ng = tanhf(acc[mi][2][r] + bi_n + rg * (acc[mi][5][r] + bh_n));
      float hp = hprev[row * 512 + j];
      hnew[row * 512 + j] = (1.f - zg) * ng + zg * hp;
    }
}

__global__ void zero_h(float* hf) {
  int i = blockIdx.x * 256 + threadIdx.x;
  hf[i] = 0.f;
}

// ---------------------------------------------------------------------------
extern "C" void kernel_launch(void* const* d_in, const int* in_sizes, int n_in,
                              void* d_out, int out_size, void* d_ws, size_t ws_size,
                              hipStream_t stream) {
  (void)in_sizes; (void)n_in; (void)out_size; (void)ws_size;
  const float* xs    = (const float*)d_in[0];
  const float* obsW  = (const float*)d_in[1];
  const float* obsb  = (const float*)d_in[2];
  const float* obsg  = (const float*)d_in[3];
  const float* obsbe = (const float*)d_in[4];
  const float* W1    = (const float*)d_in[5];
  const float* b1    = (const float*)d_in[6];
  const float* g1    = (const float*)d_in[7];
  const float* be1   = (const float*)d_in[8];
  const float* W2    = (const float*)d_in[9];
  const float* b2    = (const float*)d_in[10];
  const float* g2    = (const float*)d_in[11];
  const float* be2   = (const float*)d_in[12];
  const float* Wo    = (const float*)d_in[13];
  const float* bo    = (const float*)d_in[14];
  const float* Wih   = (const float*)d_in[15];
  const float* bih   = (const float*)d_in[16];
  const float* Whh   = (const float*)d_in[17];
  const float* bhh   = (const float*)d_in[18];

  char* p = (char*)d_ws;
  auto take = [&](size_t bytes) { char* q = p; p += (bytes + 255) & ~(size_t)255; return q; };
  unsigned short* W1t  = (unsigned short*)take((size_t)512 * 512 * 2);
  unsigned short* W2t  = (unsigned short*)take((size_t)512 * 512 * 2);
  unsigned short* Wot  = (unsigned short*)take((size_t)512 * 512 * 2);
  unsigned short* Wiht = (unsigned short*)take((size_t)1536 * 512 * 2);
  unsigned short* Whht = (unsigned short*)take((size_t)1536 * 512 * 2);
  float* hf0 = (float*)take((size_t)1024 * 512 * 4);
  float* hf1 = (float*)take((size_t)1024 * 512 * 4);
  unsigned short* Yb = (unsigned short*)take((size_t)65536 * 512 * 2);

  dim3 tb(32, 8);
  tile_weight<<<128, 256, 0, stream>>>(W1, W1t);  // first 512 of 513 rows
  tile_weight<<<128, 256, 0, stream>>>(W2, W2t);
  tile_weight<<<128, 256, 0, stream>>>(Wo, Wot);
  transpose_f2b<<<dim3(48, 16), tb, 0, stream>>>(Wih, Wiht, 512, 1536);
  transpose_f2b<<<dim3(48, 16), tb, 0, stream>>>(Whh, Whht, 512, 1536);

  obs_embed<<<16384, 256, 0, stream>>>(xs, obsW, obsb, obsg, obsbe, Yb);

  // tr = W1 row 512 (time row), folded into layer-1 bias per eval.
  ode_mega<<<1024, 512, 0, stream>>>(Yb, W1t, W2t, Wot, b1, W1 + 512 * 512, g1, be1, b2, g2,
                                     be2, bo);

  zero_h<<<2048, 256, 0, stream>>>(hf0);
  float* hf[2] = {hf0, hf1};
  for (int t = 0; t < 64; ++t) {
    int s = t & 1, d = s ^ 1;
    float* hn = (t == 63) ? (float*)d_out : hf[d];
    gru_step<<<dim3(32, 8), 256, 0, stream>>>(Yb + (size_t)t * 1024 * 512, hf[s], hn, Wiht, Whht,
                                              bih, bhh);
  }
}

// Round 9
// 2885.168 us; speedup vs baseline: 1.3194x; 1.1370x over previous
//
#include <hip/hip_runtime.h>
#include <stdint.h>

// ---------------------------------------------------------------------------
// ODE-RNN encoder, f32 I/O, bf16 MFMA internals.
// R26 = R25 ode (verbatim) + GRU restructure (ODE-style K-loop).
// R25 post-mortem: operand swap confirmed (ode 2267->2095us, MfmaUtil 38.7%,
// conflicts 6.9e7->4.2e7). Budget now: total 3280 = ode 2100 + GRU ~830
// (64 x ~13us) + rest ~350. gru_step model: 8K cyc vmem + ~10K cyc stall
// from 32 per-kk __syncthreads with unprefetched L2 loads + launch = 13us.
// R26 gru: stage A (y_t, hprev->bf16) ONCE in LDS (stride 520, 2-way bank),
// stream B via global->VGPR 2-deep dbuf (R22 pattern), ZERO in-loop
// barriers, Bg LDS deleted (51KB -> 66.6KB total, 2 blocks/CU possible).
// At 256 thr the arch cap is 65536/256=256 regs: bgl 48 + A 16 + addr ~25
// ~ 90 arch, no spill risk.
// Laws: arch-VGPR cap = 65536/threads, AGPR separate (R17-R23); ode occupancy
// pinned 1 block/CU @512thr; M=64 balances vmem/MFMA (R22); M=16 kills B
// amortization (R20); no global_load_lds (R12/13); no global RK4 state (R15).
// ---------------------------------------------------------------------------

typedef __bf16 bf16x8 __attribute__((ext_vector_type(8)));
typedef float floatx4 __attribute__((ext_vector_type(4)));

#define AP 520   // gru staged-A row stride (ushorts): 4r mod 32 banks, 2-way max
#define KSR 257  // Ks row stride (uints), row = batch row
#define REDW 9   // red row stride (float2)

static __device__ __forceinline__ float bf2f(unsigned short u) {
  union { unsigned int u32; float f; } c;
  c.u32 = ((unsigned int)u) << 16;
  return c.f;
}
static __device__ __forceinline__ unsigned short f2bf(float f) {
  union { __bf16 h; unsigned short u; } c;
  c.h = (__bf16)f;  // RNE
  return c.u;
}
static __device__ __forceinline__ unsigned int pk2(float a, float b) {
  return (unsigned int)f2bf(a) | ((unsigned int)f2bf(b) << 16);
}

// LDS-only barrier: does NOT drain vmcnt, so global prefetches stay in flight.
static __device__ __forceinline__ void barrier_lds() {
  __asm__ volatile("s_waitcnt lgkmcnt(0)\n\ts_barrier" ::: "memory");
}

// ---------------------------------------------------------------------------
// tile_weight: W (K=512 x N=512, f32 row-major) -> bf16 tiled
// [kk(16)][nt(32)][qd(4)][ml(16)][8]; element (kk,nt,qd,ml,j) = W[kk*32+qd*8+j][nt*16+ml]
// ---------------------------------------------------------------------------
__global__ void tile_weight(const float* __restrict__ src, unsigned short* __restrict__ dst) {
  int t = blockIdx.x * 256 + threadIdx.x;  // 0..32767
  int ml = t & 15, qd = (t >> 4) & 3;
  int nt = (t >> 6) & 31, kk = t >> 11;
  int n = nt * 16 + ml;
  int k0 = kk * 32 + qd * 8;
  unsigned short o[8] __attribute__((aligned(16)));
#pragma unroll
  for (int j = 0; j < 8; ++j) o[j] = f2bf(src[(size_t)(k0 + j) * 512 + n]);
  *(uint4*)(dst + (size_t)t * 8) = *(const uint4*)o;
}

// ---------------------------------------------------------------------------
// transpose + f32->bf16 (GRU weights, [n][k] flat layout)
// ---------------------------------------------------------------------------
__global__ void transpose_f2b(const float* __restrict__ src, unsigned short* __restrict__ dst,
                              int R, int C) {
  __shared__ float t[32][33];
  int c0 = blockIdx.x * 32, r0 = blockIdx.y * 32;
  int tx = threadIdx.x, ty = threadIdx.y;  // 32 x 8
#pragma unroll
  for (int i = 0; i < 32; i += 8) t[ty + i][tx] = src[(size_t)(r0 + ty + i) * C + c0 + tx];
  __syncthreads();
#pragma unroll
  for (int i = 0; i < 32; i += 8) dst[(size_t)(c0 + ty + i) * R + r0 + tx] = f2bf(t[tx][ty + i]);
}

// ---------------------------------------------------------------------------
// obs embed: y = leaky(LN(xs @ W + b)) (f32 in, bf16 out), one wave per row
// ---------------------------------------------------------------------------
__global__ __launch_bounds__(256) void obs_embed(
    const float* __restrict__ xs, const float* __restrict__ W,
    const float* __restrict__ bias, const float* __restrict__ gam,
    const float* __restrict__ bet, unsigned short* __restrict__ Y) {
  __shared__ float Wl[4096];
  const int tid = threadIdx.x, lane = tid & 63, wv = tid >> 6;
#pragma unroll
  for (int i = 0; i < 16; ++i) Wl[i * 256 + tid] = W[i * 256 + tid];
  __syncthreads();
  size_t row = (size_t)blockIdx.x * 4 + wv;
  float xf[8];
  {
    const float* xp = xs + row * 8;
#pragma unroll
    for (int k = 0; k < 8; ++k) xf[k] = xp[k];
  }
  int n0 = lane * 8;
  float a[8];
#pragma unroll
  for (int j = 0; j < 8; ++j) a[j] = bias[n0 + j];
#pragma unroll
  for (int k = 0; k < 8; ++k)
#pragma unroll
    for (int j = 0; j < 8; ++j) a[j] += xf[k] * Wl[k * 512 + n0 + j];
  float s1 = 0.f, s2 = 0.f;
#pragma unroll
  for (int j = 0; j < 8; ++j) { s1 += a[j]; s2 += a[j] * a[j]; }
#pragma unroll
  for (int off = 1; off < 64; off <<= 1) { s1 += __shfl_xor(s1, off); s2 += __shfl_xor(s2, off); }
  float mean = s1 * (1.f / 512.f);
  float rstd = rsqrtf(s2 * (1.f / 512.f) - mean * mean + 1e-5f);
  unsigned short o[8] __attribute__((aligned(16)));
#pragma unroll
  for (int j = 0; j < 8; ++j) {
    float v = (a[j] - mean) * rstd * gam[n0 + j] + bet[n0 + j];
    v = v > 0.f ? v : 0.01f * v;
    o[j] = f2bf(v);
  }
  *(uint4*)(Y + row * 512 + n0) = *(const uint4*)o;
}

// ---------------------------------------------------------------------------
// ODE megakernel, M=64, 512 thr, 8 waves; wave owns M64 x N64
// (nt = 4*wv..4*wv+3). A (64x512) in tiled LDS; B streams global->VGPR dbuf.
// Swapped MFMA: acc[mi][j][r] = Y[mi*16+ml][(4wv+j)*16 + qd*4 + r].
// ---------------------------------------------------------------------------

// element (row, n) address in tiled A (ushort index), row < 64
static __device__ __forceinline__ int a_addr(int row, int n) {
  return (((row >> 4) * 16 + (n >> 5)) * 4 + ((n >> 3) & 3)) * 128 + (row & 15) * 8 + (n & 7);
}

static __device__ __forceinline__ void bload(const unsigned short* __restrict__ Wt, int kk,
                                             int wvoff, bf16x8 (&b)[4]) {
  const unsigned short* p = Wt + (size_t)kk * 16384 + wvoff;
#pragma unroll
  for (int j = 0; j < 4; ++j) b[j] = *(const bf16x8*)(p + j * 512);
}

// acc initialized to per-n bias quad (r-component = n offset) -> bias-add
// pass and zero-init both free. a-frags chunked 2 at a time (reg cap).
// bb must hold Wt slabs {0,1} on entry; holds Wnext slabs {0,1} on exit.
static __device__ __forceinline__ void gemmS(const unsigned short* __restrict__ Wt,
                                             const unsigned short* __restrict__ Wnext,
                                             const unsigned short* As, int wvoff, int lane,
                                             const floatx4 (&bias)[4],
                                             bf16x8 (&bb)[2][4], floatx4 (&acc)[4][4]) {
#pragma unroll
  for (int mi = 0; mi < 4; ++mi)
#pragma unroll
    for (int j = 0; j < 4; ++j) acc[mi][j] = bias[j];
#pragma unroll 2
  for (int kk = 0; kk < 16; ++kk) {  // unroll 2 (dbuf parity), NOT full (R5-R8)
#pragma unroll
    for (int mh = 0; mh < 2; ++mh) {  // a-frag chunking: 2 frags in flight
      bf16x8 a0 = *(const bf16x8*)&As[((2 * mh) * 16 + kk) * 512 + lane * 8];
      bf16x8 a1 = *(const bf16x8*)&As[((2 * mh + 1) * 16 + kk) * 512 + lane * 8];
#pragma unroll
      for (int j = 0; j < 4; ++j) {
        // SWAPPED operands: D = W^T . X^T = Y^T
        acc[2 * mh][j] =
            __builtin_amdgcn_mfma_f32_16x16x32_bf16(bb[kk & 1][j], a0, acc[2 * mh][j], 0, 0, 0);
        acc[2 * mh + 1][j] =
            __builtin_amdgcn_mfma_f32_16x16x32_bf16(bb[kk & 1][j], a1, acc[2 * mh + 1][j], 0, 0, 0);
      }
    }
    // refill the just-consumed slot: kk+2 of this weight, or next weight's 0/1
    if (kk < 14) bload(Wt, kk + 2, wvoff, bb[kk & 1]);
    else bload(Wnext, kk - 14, wvoff, bb[kk & 1]);
  }
}

// LN + leaky epilogue (swapped layout): register-local row sums + 2 shfl_xor,
// per-wave stats, b64 As writes. Pg/Pb = f32 gamma/beta arrays in LDS.
static __device__ __forceinline__ void ln_epi(floatx4 (&acc)[4][4], unsigned short* As,
                                              const float* Pg, const float* Pb,
                                              int wv, int lane, float2* red) {
  const int ml = lane & 15, qd = lane >> 4;
#pragma unroll
  for (int mi = 0; mi < 4; ++mi) {
    float s1 = 0.f, s2 = 0.f;
#pragma unroll
    for (int j = 0; j < 4; ++j)
#pragma unroll
      for (int r = 0; r < 4; ++r) { float x = acc[mi][j][r]; s1 += x; s2 += x * x; }
    s1 += __shfl_xor(s1, 16); s2 += __shfl_xor(s2, 16);
    s1 += __shfl_xor(s1, 32); s2 += __shfl_xor(s2, 32);
    if (qd == 0) red[(mi * 16 + ml) * REDW + wv] = make_float2(s1, s2);
  }
  barrier_lds();  // red visible; all waves past their As a-frag reads
  float mean[4], rstd[4];
#pragma unroll
  for (int mi = 0; mi < 4; ++mi) {
    float S1 = 0.f, S2 = 0.f;
#pragma unroll
    for (int w = 0; w < 8; ++w) {
      float2 v = red[(mi * 16 + ml) * REDW + w];
      S1 += v.x; S2 += v.y;
    }
    float m = S1 * (1.f / 512.f);
    mean[mi] = m;
    rstd[mi] = rsqrtf(S2 * (1.f / 512.f) - m * m + 1e-5f);
  }
#pragma unroll
  for (int j = 0; j < 4; ++j) {
    int nb = (4 * wv + j) * 16 + qd * 4;
    floatx4 gm = *(const floatx4*)&Pg[nb];
    floatx4 bt = *(const floatx4*)&Pb[nb];
#pragma unroll
    for (int mi = 0; mi < 4; ++mi) {
      float x0 = (acc[mi][j][0] - mean[mi]) * rstd[mi] * gm[0] + bt[0];
      float x1 = (acc[mi][j][1] - mean[mi]) * rstd[mi] * gm[1] + bt[1];
      float x2 = (acc[mi][j][2] - mean[mi]) * rstd[mi] * gm[2] + bt[2];
      float x3 = (acc[mi][j][3] - mean[mi]) * rstd[mi] * gm[3] + bt[3];
      x0 = x0 > 0.f ? x0 : 0.01f * x0;
      x1 = x1 > 0.f ? x1 : 0.01f * x1;
      x2 = x2 > 0.f ? x2 : 0.01f * x2;
      x3 = x3 > 0.f ? x3 : 0.01f * x3;
      uint2 o = make_uint2(pk2(x0, x1), pk2(x2, x3));
      *(uint2*)(As + a_addr(mi * 16 + ml, nb)) = o;  // 4 consecutive n: b64
    }
  }
  barrier_lds();  // As writes visible
}

// RK4 stage (swapped layout): kv = acc (bout folded into init); h fp32 regs;
// ksum packed bf16 n-pairs in LDS Ks (per-thread slots); b64 As/Yb writes.
static __device__ __forceinline__ void stage_epi(floatx4 (&acc)[4][4], float (&h)[4][4][4],
                                                 unsigned int* Ks, unsigned short* As,
                                                 unsigned short* Yb, size_t m0,
                                                 int stg, bool last, int wv, int lane) {
  const int ml = lane & 15, qd = lane >> 4;
  barrier_lds();  // K-loop has no barriers: ensure all waves done reading As
#pragma unroll
  for (int mi = 0; mi < 4; ++mi) {
    int rowK = (mi * 16 + ml) * KSR;
#pragma unroll
    for (int j = 0; j < 4; ++j) {
      int nb = (4 * wv + j) * 16 + qd * 4;
      unsigned int yw[2];
#pragma unroll
      for (int p = 0; p < 2; ++p) {
        int kidx = rowK + (4 * wv + j) * 8 + qd * 2 + p;
        float kv0 = acc[mi][j][2 * p];
        float kv1 = acc[mi][j][2 * p + 1];
        unsigned int pk = (stg != 0) ? Ks[kidx] : 0u;
        float s0 = bf2f((unsigned short)(pk & 0xffffu));
        float s1 = bf2f((unsigned short)(pk >> 16));
        float h0 = h[mi][j][2 * p], h1 = h[mi][j][2 * p + 1];
        float y0, y1;
        if (stg == 0)      { s0 = kv0;        s1 = kv1;        y0 = h0 + 0.125f * kv0; y1 = h1 + 0.125f * kv1; }
        else if (stg == 1) { s0 += 2.f * kv0; s1 += 2.f * kv1; y0 = h0 + 0.125f * kv0; y1 = h1 + 0.125f * kv1; }
        else if (stg == 2) { s0 += 2.f * kv0; s1 += 2.f * kv1; y0 = h0 + 0.25f * kv0;  y1 = h1 + 0.25f * kv1; }
        else {
          h0 += (1.f / 24.f) * (s0 + kv0);  // dt/6, dt=0.25
          h1 += (1.f / 24.f) * (s1 + kv1);
          h[mi][j][2 * p] = h0; h[mi][j][2 * p + 1] = h1;
          y0 = h0; y1 = h1;
        }
        if (stg != 3) Ks[kidx] = pk2(s0, s1);
        yw[p] = pk2(y0, y1);
      }
      uint2 o = make_uint2(yw[0], yw[1]);
      *(uint2*)(As + a_addr(mi * 16 + ml, nb)) = o;  // 4 consecutive n: b64
      if (last && stg == 3)
        *(uint2*)(Yb + (m0 + mi * 16 + ml) * 512 + nb) = o;
    }
  }
  barrier_lds();  // As writes visible
}

__global__ __launch_bounds__(512) void ode_mega(
    unsigned short* Yb, const unsigned short* __restrict__ W1t,
    const unsigned short* __restrict__ W2t, const unsigned short* __restrict__ Wot,
    const float* __restrict__ b1, const float* __restrict__ tr, const float* __restrict__ g1,
    const float* __restrict__ be1, const float* __restrict__ b2, const float* __restrict__ g2,
    const float* __restrict__ be2, const float* __restrict__ bo) {
  __shared__ __align__(16) unsigned short As[32768];  // 64KB tiled A (64 rows)
  __shared__ __align__(16) float Pf[8 * 512];         // 16KB f32 params
  __shared__ float2 red[64 * REDW];                   // 4.5KB padded
  __shared__ __align__(16) unsigned int Ks[64 * KSR]; // 65.8KB RK4 ksum
  // total ~148.8KB <= 160KB; 1 block/CU (reg-law pinned)

  const int tid = threadIdx.x;
  const int lane = tid & 63;
  const int wv = tid >> 6;  // 0..7
  const int ml = lane & 15;
  const int qd = lane >> 4;
  const size_t m0 = (size_t)blockIdx.x * 64;
  const int wvoff = wv * 2048 + lane * 8;  // (4wv)*512 + lane*8

  // start weight prefetch immediately
  bf16x8 bb[2][4];
  bload(W1t, 0, wvoff, bb[0]);
  bload(W1t, 1, wvoff, bb[1]);

  // stage f32 params: {b1, tr, g1, be1, b2, g2, be2, bo}
  {
    const float* srcs[8] = {b1, tr, g1, be1, b2, g2, be2, bo};
#pragma unroll
    for (int v = 0; v < 8; ++v) Pf[v * 512 + tid] = srcs[v][tid];
  }

  // stage As: thread owns row r = tid>>3, chunks c = (tid&7) + i*8, i=0..7
  {
    int r = tid >> 3;       // 0..63
    int c0 = tid & 7;
#pragma unroll
    for (int i = 0; i < 8; ++i) {
      int c = c0 + i * 8;   // 0..63
      uint4 v = *(const uint4*)(Yb + (m0 + r) * 512 + c * 8);
      int dst = (((r >> 4) * 16 + (c >> 2)) * 4 + (c & 3)) * 128 + (r & 15) * 8;
      *(uint4*)(As + dst) = v;
    }
  }
  barrier_lds();

  float h[4][4][4];  // fp32 ODE state, swapped layout (64 elems/thread)
#pragma unroll
  for (int mi = 0; mi < 4; ++mi)
#pragma unroll
    for (int j = 0; j < 4; ++j) {
      int nb = (4 * wv + j) * 16 + qd * 4;
      uint2 v = *(const uint2*)(As + a_addr(mi * 16 + ml, nb));
      h[mi][j][0] = bf2f((unsigned short)(v.x & 0xffffu));
      h[mi][j][1] = bf2f((unsigned short)(v.x >> 16));
      h[mi][j][2] = bf2f((unsigned short)(v.y & 0xffffu));
      h[mi][j][3] = bf2f((unsigned short)(v.y >> 16));
    }

  for (int e = 0; e < 16; ++e) {  // 4 RK4 steps x 4 stages
    int stg = e & 3;
    float tval = 0.25f * (float)(e >> 2) + ((stg == 3) ? 0.25f : (stg ? 0.125f : 0.f));
    floatx4 acc[4][4];
    floatx4 bias[4];

#pragma unroll
    for (int j = 0; j < 4; ++j) {  // layer-1 bias quad (time row folded)
      int nb = (4 * wv + j) * 16 + qd * 4;
      floatx4 vb = *(const floatx4*)&Pf[0 * 512 + nb];
      floatx4 vt = *(const floatx4*)&Pf[1 * 512 + nb];
#pragma unroll
      for (int r = 0; r < 4; ++r) bias[j][r] = vb[r] + tval * vt[r];
    }
    gemmS(W1t, W2t, As, wvoff, lane, bias, bb, acc);
    ln_epi(acc, As, Pf + 2 * 512, Pf + 3 * 512, wv, lane, red);

#pragma unroll
    for (int j = 0; j < 4; ++j) {  // layer-2 bias quad
      int nb = (4 * wv + j) * 16 + qd * 4;
      bias[j] = *(const floatx4*)&Pf[4 * 512 + nb];
    }
    gemmS(W2t, Wot, As, wvoff, lane, bias, bb, acc);
    ln_epi(acc, As, Pf + 5 * 512, Pf + 6 * 512, wv, lane, red);

#pragma unroll
    for (int j = 0; j < 4; ++j) {  // out-layer bias quad (bo)
      int nb = (4 * wv + j) * 16 + qd * 4;
      bias[j] = *(const floatx4*)&Pf[7 * 512 + nb];
    }
    gemmS(Wot, W1t, As, wvoff, lane, bias, bb, acc);  // preloads next eval's W1
    stage_epi(acc, h, Ks, As, Yb, m0, stg, e == 15, wv, lane);
  }
}

// ---------------------------------------------------------------------------
// GRU step: gi = y_t @ W_ih, gh = h_prev @ W_hh, gates.
// grid (32, 8): 32 rows x 64 gate-cols per block, 4 waves.
// R26: A (y_t, hprev->bf16) staged ONCE in LDS (stride AP=520, 2-way bank);
// B streams global->VGPR 2-deep dbuf; ZERO in-loop barriers.
// ---------------------------------------------------------------------------
__global__ __launch_bounds__(256) void gru_step(
    const unsigned short* __restrict__ Yt, const float* __restrict__ hprev,
    float* __restrict__ hnew, const unsigned short* __restrict__ Wiht,
    const unsigned short* __restrict__ Whht, const float* __restrict__ bih,
    const float* __restrict__ bhh) {
  __shared__ __align__(16) unsigned short Ay[32 * AP];
  __shared__ __align__(16) unsigned short Ah[32 * AP];
  const int tid = threadIdx.x, lane = tid & 63, wv = tid >> 6;
  const int ml = lane & 15, qd = lane >> 4;
  const int m0 = blockIdx.x * 32;
  const int j0 = blockIdx.y * 64;

  // B base pointers for this thread's 6 gate fragments (row = gate*512 +
  // j0 + 16*wv + ml; k-offset qd*8 baked in)
  const unsigned short* bp[6];
#pragma unroll
  for (int g = 0; g < 6; ++g) {
    const unsigned short* mat = (g < 3) ? Wiht : Whht;
    int gate = (g < 3) ? g : (g - 3);
    bp[g] = mat + (size_t)(gate * 512 + j0 + 16 * wv + ml) * 512 + qd * 8;
  }
  // prefetch B for kk = 0, 1 (in flight across the A staging below)
  bf16x8 bgl[2][6];
#pragma unroll
  for (int g = 0; g < 6; ++g) bgl[0][g] = *(const bf16x8*)(bp[g]);
#pragma unroll
  for (int g = 0; g < 6; ++g) bgl[1][g] = *(const bf16x8*)(bp[g] + 32);

  // stage A once: thread owns row r = tid>>3, col chunks c = (tid&7)+8i
  {
    int r = tid >> 3, c0 = tid & 7;
#pragma unroll
    for (int i = 0; i < 8; ++i) {
      int c = c0 + i * 8;
      *(uint4*)(Ay + r * AP + c * 8) = *(const uint4*)(Yt + (size_t)(m0 + r) * 512 + c * 8);
    }
#pragma unroll
    for (int i = 0; i < 8; ++i) {
      int c = c0 + i * 8;
      const float* s = hprev + (size_t)(m0 + r) * 512 + c * 8;
      unsigned short o[8] __attribute__((aligned(16)));
#pragma unroll
      for (int j = 0; j < 8; ++j) o[j] = f2bf(s[j]);
      *(uint4*)(Ah + r * AP + c * 8) = *(const uint4*)o;
    }
  }
  __syncthreads();

  floatx4 acc[2][6];
#pragma unroll
  for (int mi = 0; mi < 2; ++mi)
#pragma unroll
    for (int g = 0; g < 6; ++g) acc[mi][g] = 0.f;

#pragma unroll 2
  for (int kk = 0; kk < 16; ++kk) {  // barrier-free: A in LDS, B in reg dbuf
    bf16x8 ay[2], ah[2];
#pragma unroll
    for (int mi = 0; mi < 2; ++mi) {
      ay[mi] = *(const bf16x8*)&Ay[(16 * mi + ml) * AP + kk * 32 + qd * 8];
      ah[mi] = *(const bf16x8*)&Ah[(16 * mi + ml) * AP + kk * 32 + qd * 8];
    }
#pragma unroll
    for (int g = 0; g < 6; ++g) {
#pragma unroll
      for (int mi = 0; mi < 2; ++mi)
        acc[mi][g] = __builtin_amdgcn_mfma_f32_16x16x32_bf16((g < 3) ? ay[mi] : ah[mi],
                                                             bgl[kk & 1][g], acc[mi][g], 0, 0, 0);
    }
    if (kk < 14) {
#pragma unroll
      for (int g = 0; g < 6; ++g) bgl[kk & 1][g] = *(const bf16x8*)(bp[g] + (kk + 2) * 32);
    }
  }

  int j = j0 + 16 * wv + ml;
  float bi_r = bih[j], bi_z = bih[512 + j], bi_n = bih[1024 + j];
  float bh_r = bhh[j], bh_z = bhh[512 + j], bh_n = bhh[1024 + j];
#pragma unroll
  for (int mi = 0; mi < 2; ++mi)
#pragma unroll
    for (int r = 0; r < 4; ++r) {
      size_t row = (size_t)(m0 + 16 * mi + 4 * qd + r);
      float rg = acc[mi][0][r] + bi_r + acc[mi][3][r] + bh_r;
      rg = 1.f / (1.f + __expf(-rg));
      float zg = acc[mi][1][r] + bi_z + acc[mi][4][r] + bh_z;
      zg = 1.f / (1.f + __expf(-zg));
      float ng = tanhf(acc[mi][2][r] + bi_n + rg * (acc[mi][5][r] + bh_n));
      float hp = hprev[row * 512 + j];
      hnew[row * 512 + j] = (1.f - zg) * ng + zg * hp;
    }
}

__global__ void zero_h(float* hf) {
  int i = blockIdx.x * 256 + threadIdx.x;
  hf[i] = 0.f;
}

// ---------------------------------------------------------------------------
extern "C" void kernel_launch(void* const* d_in, const int* in_sizes, int n_in,
                              void* d_out, int out_size, void* d_ws, size_t ws_size,
                              hipStream_t stream) {
  (void)in_sizes; (void)n_in; (void)out_size; (void)ws_size;
  const float* xs    = (const float*)d_in[0];
  const float* obsW  = (const float*)d_in[1];
  const float* obsb  = (const float*)d_in[2];
  const float* obsg  = (const float*)d_in[3];
  const float* obsbe = (const float*)d_in[4];
  const float* W1    = (const float*)d_in[5];
  const float* b1    = (const float*)d_in[6];
  const float* g1    = (const float*)d_in[7];
  const float* be1   = (const float*)d_in[8];
  const float* W2    = (const float*)d_in[9];
  const float* b2    = (const float*)d_in[10];
  const float* g2    = (const float*)d_in[11];
  const float* be2   = (const float*)d_in[12];
  const float* Wo    = (const float*)d_in[13];
  const float* bo    = (const float*)d_in[14];
  const float* Wih   = (const float*)d_in[15];
  const float* bih   = (const float*)d_in[16];
  const float* Whh   = (const float*)d_in[17];
  const float* bhh   = (const float*)d_in[18];

  char* p = (char*)d_ws;
  auto take = [&](size_t bytes) { char* q = p; p += (bytes + 255) & ~(size_t)255; return q; };
  unsigned short* W1t  = (unsigned short*)take((size_t)512 * 512 * 2);
  unsigned short* W2t  = (unsigned short*)take((size_t)512 * 512 * 2);
  unsigned short* Wot  = (unsigned short*)take((size_t)512 * 512 * 2);
  unsigned short* Wiht = (unsigned short*)take((size_t)1536 * 512 * 2);
  unsigned short* Whht = (unsigned short*)take((size_t)1536 * 512 * 2);
  float* hf0 = (float*)take((size_t)1024 * 512 * 4);
  float* hf1 = (float*)take((size_t)1024 * 512 * 4);
  unsigned short* Yb = (unsigned short*)take((size_t)65536 * 512 * 2);

  dim3 tb(32, 8);
  tile_weight<<<128, 256, 0, stream>>>(W1, W1t);  // first 512 of 513 rows
  tile_weight<<<128, 256, 0, stream>>>(W2, W2t);
  tile_weight<<<128, 256, 0, stream>>>(Wo, Wot);
  transpose_f2b<<<dim3(48, 16), tb, 0, stream>>>(Wih, Wiht, 512, 1536);
  transpose_f2b<<<dim3(48, 16), tb, 0, stream>>>(Whh, Whht, 512, 1536);

  obs_embed<<<16384, 256, 0, stream>>>(xs, obsW, obsb, obsg, obsbe, Yb);

  // tr = W1 row 512 (time row), folded into layer-1 bias per eval.
  ode_mega<<<1024, 512, 0, stream>>>(Yb, W1t, W2t, Wot, b1, W1 + 512 * 512, g1, be1, b2, g2,
                                     be2, bo);

  zero_h<<<2048, 256, 0, stream>>>(hf0);
  float* hf[2] = {hf0, hf1};
  for (int t = 0; t < 64; ++t) {
    int s = t & 1, d = s ^ 1;
    float* hn = (t == 63) ? (float*)d_out : hf[d];
    gru_step<<<dim3(32, 8), 256, 0, stream>>>(Yb + (size_t)t * 1024 * 512, hf[s], hn, Wiht, Whht,
                                              bih, bhh);
  }
}